// Round 17
// baseline (200.648 us; speedup 1.0000x reference)
//
#include <hip/hip_runtime.h>
#include <hip/hip_bf16.h>
#include <math.h>

static constexpr int Bc = 2;
static constexpr int Sc = 2048;
static constexpr int Dc = 1024;
static constexpr int Hc = 2048;
static constexpr int Ac = 128;
static constexpr int Ec = 8;
static constexpr int GSc = 4;
static constexpr int Gc = 2;
static constexpr int Nc = Bc * Sc;   // 4096 tokens
static constexpr float LN_EPSc = 1e-5f;
static constexpr int RBLK = 512;     // router blocks

typedef __attribute__((ext_vector_type(8))) short bf16x8;
typedef __attribute__((ext_vector_type(4))) float f32x4;
typedef __attribute__((ext_vector_type(4))) unsigned short us4;

__device__ __forceinline__ unsigned short f2b(float f) {
    union { float f; unsigned u; } v; v.f = f;
    return (unsigned short)((v.u + 0x7FFFu + ((v.u >> 16) & 1u)) >> 16);
}
__device__ __forceinline__ float b2f(unsigned short h) {
    union { unsigned u; float f; } v; v.u = (unsigned)h << 16; return v.f;
}
__device__ __forceinline__ float fsilu(float x) {
    return x / (1.f + __expf(-x));
}

#define GLOAD16(g, l) __builtin_amdgcn_global_load_lds( \
    (const __attribute__((address_space(1))) void*)(g), \
    (__attribute__((address_space(3))) void*)(l), 16, 0, 0)

// 2-D L2-panel swizzle
__device__ __forceinline__ void panel_swizzle(int gx, int gy, int PR, int PC,
                                              int& bx, int& by)
{
    const int nwg = gx * gy;
    const int flat = blockIdx.y * gx + blockIdx.x;
    const int ord = (flat & 7) * (nwg >> 3) + (flat >> 3);   // XCD chunking
    const int srw = gx * PR;            // tiles per super-row
    const int sr = ord / srw;
    int rem = ord % srw;
    const int pi = rem / (PR * PC);
    rem %= (PR * PC);
    by = sr * PR + rem / PC;
    bx = pi * PC + rem % PC;
}

// ---------------- bf16 MFMA GEMM, 128x128 tile, BK=64, bank-swizzled ----------
template<int EPI>
__global__ __launch_bounds__(256, 4) void mgemm(
    const unsigned short* __restrict__ Ag, const unsigned short* __restrict__ Bg,
    void* __restrict__ Cg, int N, int K, int lda, int ldb, int PR, int PC, float alpha,
    float* __restrict__ aux, void* __restrict__ aux2,
    long long sA, long long sB, long long sC)
{
    __shared__ unsigned short As[128 * 64];
    __shared__ unsigned short Bs[128 * 64];
    const unsigned short* A = Ag + (long long)blockIdx.z * sA;
    const unsigned short* B = Bg + (long long)blockIdx.z * sB;
    float* fC = (float*)Cg + (long long)blockIdx.z * sC;
    unsigned short* usC = (unsigned short*)Cg + (long long)blockIdx.z * sC;

    int bx, by;
    panel_swizzle(gridDim.x, gridDim.y, PR, PC, bx, by);
    const int bm = by * 128, bn = bx * 128;

    const int tid = threadIdx.x;
    const int w = tid >> 6, l = tid & 63;
    const int wm = (w >> 1) * 64, wn = (w & 1) * 64;
    const int fr = l & 15, g = l >> 4;

    const f32x4 zero = { 0.f, 0.f, 0.f, 0.f };
    f32x4 acc[4][4];
    #pragma unroll
    for (int i = 0; i < 4; ++i)
        #pragma unroll
        for (int j = 0; j < 4; ++j) acc[i][j] = zero;

    for (int k0 = 0; k0 < K; k0 += 64) {
        #pragma unroll
        for (int p = 0; p < 4; ++p) {
            const int c = p * 256 + tid;
            const int row = c >> 3;
            const int gch = (c & 7) ^ ((c >> 4) & 7);
            GLOAD16(A + (long long)(bm + row) * lda + k0 + gch * 8, &As[c * 8]);
            GLOAD16(B + (long long)(bn + row) * ldb + k0 + gch * 8, &Bs[c * 8]);
        }
        __syncthreads();
        #pragma unroll
        for (int h = 0; h < 2; ++h) {
            bf16x8 af[4], bfv[4];
            #pragma unroll
            for (int i = 0; i < 4; ++i) {
                const int ra = wm + i * 16 + fr;
                af[i]  = *(const bf16x8*)&As[ra * 64 + ((h * 4 + g) ^ ((ra >> 1) & 7)) * 8];
                const int rb = wn + i * 16 + fr;
                bfv[i] = *(const bf16x8*)&Bs[rb * 64 + ((h * 4 + g) ^ ((rb >> 1) & 7)) * 8];
            }
            #pragma unroll
            for (int i = 0; i < 4; ++i)
                #pragma unroll
                for (int j = 0; j < 4; ++j)
                    acc[i][j] = __builtin_amdgcn_mfma_f32_16x16x32_bf16(af[i], bfv[j], acc[i][j], 0, 0, 0);
        }
        __syncthreads();
    }

    if (EPI == 9) {
        if (bn < 2 * Hc) {
            #pragma unroll
            for (int mi = 0; mi < 4; ++mi) {
                #pragma unroll
                for (int j = 0; j < 2; ++j) {
                    #pragma unroll
                    for (int jr = 0; jr < 4; ++jr) {
                        const long long row = bm + wm + mi * 16 + g * 4 + jr;
                        const long long colh = ((bn + wn) >> 1) + j * 16 + fr;
                        const float gv = acc[mi][2 * j][jr];
                        const float uv = acc[mi][2 * j + 1][jr];
                        usC[row * Hc + colh] = f2b(fsilu(gv) * uv);
                    }
                }
            }
        } else {
            unsigned short* preb = (unsigned short*)aux2;
            #pragma unroll
            for (int mi = 0; mi < 4; ++mi) {
                #pragma unroll
                for (int ni = 0; ni < 4; ++ni) {
                    #pragma unroll
                    for (int jr = 0; jr < 4; ++jr) {
                        const long long row = bm + wm + mi * 16 + g * 4 + jr;
                        const int lc = wn + ni * 16 + fr;
                        const float v = acc[mi][ni][jr];
                        aux[row * Ac + lc] = v;
                        preb[row * Ac + lc] = f2b(v);
                    }
                }
            }
        }
    } else {
        #pragma unroll
        for (int mi = 0; mi < 4; ++mi)
            #pragma unroll
            for (int ni = 0; ni < 4; ++ni)
                #pragma unroll
                for (int jr = 0; jr < 4; ++jr) {
                    const long long row = bm + wm + mi * 16 + g * 4 + jr;
                    const long long col = bn + wn + ni * 16 + fr;
                    const long long idx = row * (long long)N + col;
                    const float v = acc[mi][ni][jr];
                    if (EPI == 0) fC[idx] = v;
                    else usC[idx] = f2b(alpha * v);
                }
    }
}

// ---------------- bf16 MFMA GEMM, 128x64 tile (f32 out), BK=32, 2-axis z -----
__global__ __launch_bounds__(256, 2) void mgemm64(
    const unsigned short* __restrict__ Ag, const unsigned short* __restrict__ Bg,
    float* __restrict__ Cg, int N, int K, int lda, int ldb, int zmod,
    long long sA1, long long sB1, long long sC1,
    long long sA2, long long sB2, long long sC2)
{
    __shared__ unsigned short As[128 * 32];
    __shared__ unsigned short Bs[64 * 32];
    const int z1 = blockIdx.z % zmod, z2 = blockIdx.z / zmod;
    const unsigned short* A = Ag + (long long)z1 * sA1 + (long long)z2 * sA2;
    const unsigned short* B = Bg + (long long)z1 * sB1 + (long long)z2 * sB2;
    float* fC = Cg + (long long)z1 * sC1 + (long long)z2 * sC2;

    const int nwg = gridDim.x * gridDim.y;
    const int flat = blockIdx.y * gridDim.x + blockIdx.x;
    const int swz = (flat & 7) * (nwg >> 3) + (flat >> 3);
    const int bx = swz % gridDim.x, by = swz / gridDim.x;
    const int bm = by * 128, bn = bx * 64;

    const int tid = threadIdx.x;
    const int w = tid >> 6, l = tid & 63;
    const int wm = (w >> 1) * 64, wn = (w & 1) * 32;
    const int fr = l & 15, g = l >> 4;

    const f32x4 zero = { 0.f, 0.f, 0.f, 0.f };
    f32x4 acc[4][2];
    #pragma unroll
    for (int i = 0; i < 4; ++i)
        #pragma unroll
        for (int j = 0; j < 2; ++j) acc[i][j] = zero;

    for (int k0 = 0; k0 < K; k0 += 32) {
        #pragma unroll
        for (int p = 0; p < 2; ++p) {
            const int c = p * 256 + tid;
            GLOAD16(A + (long long)(bm + (c >> 2)) * lda + k0 + (c & 3) * 8, &As[c * 8]);
        }
        GLOAD16(B + (long long)(bn + (tid >> 2)) * ldb + k0 + (tid & 3) * 8, &Bs[tid * 8]);
        __syncthreads();
        bf16x8 af[4], bfv[2];
        #pragma unroll
        for (int i = 0; i < 4; ++i)
            af[i]  = *(const bf16x8*)&As[(wm + i * 16 + fr) * 32 + g * 8];
        #pragma unroll
        for (int j = 0; j < 2; ++j)
            bfv[j] = *(const bf16x8*)&Bs[(wn + j * 16 + fr) * 32 + g * 8];
        #pragma unroll
        for (int i = 0; i < 4; ++i)
            #pragma unroll
            for (int j = 0; j < 2; ++j)
                acc[i][j] = __builtin_amdgcn_mfma_f32_16x16x32_bf16(af[i], bfv[j], acc[i][j], 0, 0, 0);
        __syncthreads();
    }

    #pragma unroll
    for (int mi = 0; mi < 4; ++mi)
        #pragma unroll
        for (int ni = 0; ni < 2; ++ni)
            #pragma unroll
            for (int jr = 0; jr < 4; ++jr) {
                const long long row = bm + wm + mi * 16 + g * 4 + jr;
                const long long col = bn + wn + ni * 16 + fr;
                fC[row * (long long)N + col] = acc[mi][ni][jr];
            }
}

// ---------------- fused aw+adapt: direct-global fragments, QBLK=64 ------------
__global__ __launch_bounds__(256, 2) void fadapt_k(
    const unsigned short* __restrict__ adapt_in,
    const unsigned short* __restrict__ adapt_out,
    const unsigned short* __restrict__ adapt_inT,
    float* __restrict__ partial)
{
    __shared__ unsigned short P_lds[4 * 64 * 32];   // [ks][qrow][chunk-swizzled]

    const int b = blockIdx.z;
    const int q0 = blockIdx.y * 64;
    const int t0 = blockIdx.x * 256;

    const unsigned short* Qg = adapt_in + (long long)b * Sc * Ac;
    const unsigned short* Kg = adapt_out + (long long)b * Sc * Ac;
    const unsigned short* Vt = adapt_inT + (long long)b * Ac * Sc;

    const int tid = threadIdx.x;
    const int w = tid >> 6, l = tid & 63;
    const int wm = (w >> 1) * 32, wn = (w & 1) * 64;
    const int fr = l & 15, g = l >> 4;

    bf16x8 qf[2][4];
    #pragma unroll
    for (int i = 0; i < 2; ++i) {
        const long long ra = q0 + wm + i * 16 + fr;
        #pragma unroll
        for (int ks = 0; ks < 4; ++ks)
            qf[i][ks] = *(const bf16x8*)&Qg[ra * Ac + ks * 32 + g * 8];
    }

    const f32x4 zero = { 0.f, 0.f, 0.f, 0.f };
    f32x4 acc[2][4];
    #pragma unroll
    for (int i = 0; i < 2; ++i)
        #pragma unroll
        for (int j = 0; j < 4; ++j) acc[i][j] = zero;

    #pragma unroll 1
    for (int ts = 0; ts < 2; ++ts) {
        const int t1 = t0 + ts * 128;
        f32x4 sacc[2][4];
        #pragma unroll
        for (int i = 0; i < 2; ++i)
            #pragma unroll
            for (int j = 0; j < 4; ++j) sacc[i][j] = zero;
        #pragma unroll
        for (int ks = 0; ks < 4; ++ks) {
            bf16x8 bfv[4];
            #pragma unroll
            for (int j = 0; j < 4; ++j) {
                const long long rb = t1 + wn + j * 16 + fr;
                bfv[j] = *(const bf16x8*)&Kg[rb * Ac + ks * 32 + g * 8];
            }
            #pragma unroll
            for (int i = 0; i < 2; ++i)
                #pragma unroll
                for (int j = 0; j < 4; ++j)
                    sacc[i][j] = __builtin_amdgcn_mfma_f32_16x16x32_bf16(qf[i][ks], bfv[j], sacc[i][j], 0, 0, 0);
        }
        __syncthreads();
        #pragma unroll
        for (int mi = 0; mi < 2; ++mi) {
            #pragma unroll
            for (int ni = 0; ni < 4; ++ni) {
                const int t = wn + ni * 16 + fr;
                const int tl = t & 31;
                const int kbase = (t >> 5) * 2048;
                #pragma unroll
                for (int jr = 0; jr < 4; ++jr) {
                    const int row = wm + mi * 16 + g * 4 + jr;
                    float v = sacc[mi][ni][jr];
                    v = fminf(fmaxf(v, -5.f), 5.f);
                    const int pos = (((tl >> 3) ^ ((row >> 1) & 3)) << 3) + (tl & 7);
                    P_lds[kbase + row * 32 + pos] = f2b(fsilu(v));
                }
            }
        }
        __syncthreads();
        #pragma unroll
        for (int ks = 0; ks < 4; ++ks) {
            bf16x8 af[2], bfv[4];
            #pragma unroll
            for (int i = 0; i < 2; ++i) {
                const int ra = wm + i * 16 + fr;
                af[i] = *(const bf16x8*)&P_lds[ks * 2048 + ra * 32 + (g ^ ((ra >> 1) & 3)) * 8];
            }
            #pragma unroll
            for (int j = 0; j < 4; ++j) {
                const long long rb = wn + j * 16 + fr;
                bfv[j] = *(const bf16x8*)&Vt[rb * Sc + t1 + ks * 32 + g * 8];
            }
            #pragma unroll
            for (int i = 0; i < 2; ++i)
                #pragma unroll
                for (int j = 0; j < 4; ++j)
                    acc[i][j] = __builtin_amdgcn_mfma_f32_16x16x32_bf16(af[i], bfv[j], acc[i][j], 0, 0, 0);
        }
    }

    float* op = partial + ((long long)blockIdx.x * Bc + b) * Sc * Ac;
    #pragma unroll
    for (int mi = 0; mi < 2; ++mi)
        #pragma unroll
        for (int ni = 0; ni < 4; ++ni)
            #pragma unroll
            for (int jr = 0; jr < 4; ++jr) {
                const long long row = q0 + wm + mi * 16 + g * 4 + jr;
                const long long col = wn + ni * 16 + fr;
                op[row * Ac + col] = acc[mi][ni][jr];
            }
}

// ---------------- final fused 3-phase GEMM, 128x64 tile, BK=64, swizzled ------
__global__ __launch_bounds__(256, 2) void final_k(
    const unsigned short* __restrict__ hidden, const unsigned short* __restrict__ Wd,
    const unsigned short* __restrict__ adaptb, const unsigned short* __restrict__ Wdap,
    const unsigned short* __restrict__ h2v, const unsigned short* __restrict__ Wopep,
    const float* __restrict__ dmsum, float* __restrict__ out)
{
    __shared__ unsigned short As[128 * 64];
    __shared__ unsigned short Bs[64 * 64];

    int bx, by;
    panel_swizzle(gridDim.x, gridDim.y, 4, 4, bx, by);
    const int bm = by * 128, bn = bx * 64;

    const int tid = threadIdx.x;
    const int w = tid >> 6, l = tid & 63;
    const int wm = (w >> 1) * 64, wn = (w & 1) * 32;
    const int fr = l & 15, g = l >> 4;

    const f32x4 zero = { 0.f, 0.f, 0.f, 0.f };
    f32x4 acc[4][2];
    #pragma unroll
    for (int i = 0; i < 4; ++i)
        #pragma unroll
        for (int j = 0; j < 2; ++j) acc[i][j] = zero;

    const unsigned short* Ap[3] = { hidden, adaptb, h2v };
    const unsigned short* Bp[3] = { Wd, Wdap, Wopep };
    const int Ks[3] = { Hc, Ac, Ac };

    #pragma unroll 1
    for (int ph = 0; ph < 3; ++ph) {
        if (ph == 2) {
            #pragma unroll
            for (int mi = 0; mi < 4; ++mi)
                #pragma unroll
                for (int jr = 0; jr < 4; ++jr) {
                    const float rs = dmsum[bm + wm + mi * 16 + g * 4 + jr];
                    #pragma unroll
                    for (int ni = 0; ni < 2; ++ni) acc[mi][ni][jr] *= rs;
                }
        }
        const unsigned short* A = Ap[ph];
        const unsigned short* B = Bp[ph];
        const int K = Ks[ph];
        for (int k0 = 0; k0 < K; k0 += 64) {
            #pragma unroll
            for (int p = 0; p < 4; ++p) {
                const int c = p * 256 + tid;
                const int row = c >> 3;
                const int gch = (c & 7) ^ ((c >> 4) & 7);
                GLOAD16(A + (long long)(bm + row) * K + k0 + gch * 8, &As[c * 8]);
            }
            #pragma unroll
            for (int p = 0; p < 2; ++p) {
                const int c = p * 256 + tid;
                const int row = c >> 3;
                const int gch = (c & 7) ^ ((c >> 4) & 7);
                GLOAD16(B + (long long)(bn + row) * K + k0 + gch * 8, &Bs[c * 8]);
            }
            __syncthreads();
            #pragma unroll
            for (int h = 0; h < 2; ++h) {
                bf16x8 af[4], bfv[2];
                #pragma unroll
                for (int i = 0; i < 4; ++i) {
                    const int ra = wm + i * 16 + fr;
                    af[i]  = *(const bf16x8*)&As[ra * 64 + ((h * 4 + g) ^ ((ra >> 1) & 7)) * 8];
                }
                #pragma unroll
                for (int j = 0; j < 2; ++j) {
                    const int rb = wn + j * 16 + fr;
                    bfv[j] = *(const bf16x8*)&Bs[rb * 64 + ((h * 4 + g) ^ ((rb >> 1) & 7)) * 8];
                }
                #pragma unroll
                for (int i = 0; i < 4; ++i)
                    #pragma unroll
                    for (int j = 0; j < 2; ++j)
                        acc[i][j] = __builtin_amdgcn_mfma_f32_16x16x32_bf16(af[i], bfv[j], acc[i][j], 0, 0, 0);
            }
            __syncthreads();
        }
    }

    #pragma unroll
    for (int mi = 0; mi < 4; ++mi)
        #pragma unroll
        for (int ni = 0; ni < 2; ++ni)
            #pragma unroll
            for (int jr = 0; jr < 4; ++jr) {
                const long long row = bm + wm + mi * 16 + g * 4 + jr;
                const long long col = bn + wn + ni * 16 + fr;
                out[row * (long long)Dc + col] = acc[mi][ni][jr];
            }
}

// ---------------- partial-sum reduce: out = alpha * sum_p in[p*stride + i] ----
template<int NP, int BF>
__global__ __launch_bounds__(256) void reduce_k(const float* __restrict__ in,
                                                void* __restrict__ outp,
                                                long long pstride, int n4, float alpha)
{
    for (int i = blockIdx.x * 256 + threadIdx.x; i < n4; i += gridDim.x * 256) {
        float4 s = ((const float4*)in)[i];
        #pragma unroll
        for (int p = 1; p < NP; ++p) {
            const float4 v = ((const float4*)(in + (long long)p * pstride))[i];
            s.x += v.x; s.y += v.y; s.z += v.z; s.w += v.w;
        }
        s.x *= alpha; s.y *= alpha; s.z *= alpha; s.w *= alpha;
        if (BF) {
            us4 o = { f2b(s.x), f2b(s.y), f2b(s.z), f2b(s.w) };
            ((us4*)outp)[i] = o;
        } else {
            ((float4*)outp)[i] = s;
        }
    }
}

// ---------------- standalone weight prep (round-15 version) -------------------
struct PrepArgs {
    const float* csrc[4]; unsigned short* cdst[4]; int cn4[4];
    const float* Wg; const float* Wu; const float* Wpre; unsigned short* Wcat;
    const float* tin0; const float* tin1; unsigned short* tout0; unsigned short* tout1;
};
__global__ __launch_bounds__(256) void prep_k(PrepArgs a)
{
    __shared__ float T[64][68];
    const int y = blockIdx.y;
    if (y < 4) {
        const float4* s = (const float4*)a.csrc[y];
        us4* d = (us4*)a.cdst[y];
        const int n = a.cn4[y];
        for (int i = blockIdx.x * 256 + threadIdx.x; i < n; i += gridDim.x * 256) {
            const float4 v = s[i];
            us4 o;
            o.x = f2b(v.x); o.y = f2b(v.y); o.z = f2b(v.z); o.w = f2b(v.w);
            d[i] = o;
        }
    } else if (y == 4) {
        const int total = (2 * Hc + Ac) * 256;
        for (int u = blockIdx.x * 256 + threadIdx.x; u < total; u += gridDim.x * 256) {
            const int r = u >> 8, t = u & 255;
            const float* src; int srcrow;
            if (r < 2 * Hc) {
                const int b = r >> 5, wq = r & 31;
                src = (wq < 16) ? a.Wg : a.Wu;
                srcrow = b * 16 + (wq & 15);
            } else {
                src = a.Wpre;
                srcrow = r - 2 * Hc;
            }
            const float4 v = ((const float4*)(src + (long long)srcrow * Dc))[t];
            us4 o;
            o.x = f2b(v.x); o.y = f2b(v.y); o.z = f2b(v.z); o.w = f2b(v.w);
            ((us4*)(a.Wcat + (long long)r * Dc))[t] = o;
        }
    } else {
        const int rr = threadIdx.x >> 4, cc = (threadIdx.x & 15) * 4;
        for (int tb = blockIdx.x; tb < 128; tb += gridDim.x) {
            const int z = tb >> 6, rem = tb & 63;
            const int a0 = (rem >> 5) * 64, t0 = (rem & 31) * 64;
            const float* in = z ? a.tin1 : a.tin0;
            unsigned short* outp = z ? a.tout1 : a.tout0;
            __syncthreads();
            #pragma unroll
            for (int p = 0; p < 4; ++p) {
                const int row = p * 16 + rr;
                *(float4*)&T[row][cc] = *(const float4*)&in[(long long)(t0 + row) * Ac + a0 + cc];
            }
            __syncthreads();
            #pragma unroll
            for (int p = 0; p < 4; ++p) {
                const int ar = p * 16 + rr;
                us4 o;
                o.x = f2b(T[cc + 0][ar]); o.y = f2b(T[cc + 1][ar]);
                o.z = f2b(T[cc + 2][ar]); o.w = f2b(T[cc + 3][ar]);
                *(us4*)&outp[(long long)(a0 + ar) * Hc + t0 + cc] = o;
            }
        }
    }
}

// ---------------- standalone slim router (round-15 version) -------------------
__global__ __launch_bounds__(256) void router_k(const float* __restrict__ x,
                                                const float* __restrict__ W_rg,
                                                const float* __restrict__ W_re,
                                                int* __restrict__ eidx, float* __restrict__ fw,
                                                float* __restrict__ dmsum,
                                                float* __restrict__ rpart,
                                                unsigned short* __restrict__ xb)
{
    const int wv = threadIdx.x >> 6;
    const int lane = threadIdx.x & 63;
    float load8[8] = {0.f, 0.f, 0.f, 0.f, 0.f, 0.f, 0.f, 0.f};
    float sqg = 0.f, sqe = 0.f;

    #pragma unroll
    for (int it = 0; it < 2; ++it) {
        const int t = blockIdx.x * 8 + wv * 2 + it;
        const float* xr = x + (long long)t * Dc;
        float a0 = 0, a1 = 0, a2 = 0, a3 = 0, a4 = 0, a5 = 0;
        #pragma unroll
        for (int j = 0; j < 16; ++j) {
            const int d = lane + 64 * j;
            const float xv = xr[d];
            xb[(long long)t * Dc + d] = f2b(xv);
            a0 += xv * W_rg[d];          a1 += xv * W_rg[Dc + d];
            a2 += xv * W_re[d];          a3 += xv * W_re[Dc + d];
            a4 += xv * W_re[2 * Dc + d]; a5 += xv * W_re[3 * Dc + d];
        }
        #pragma unroll
        for (int o = 32; o > 0; o >>= 1) {
            a0 += __shfl_xor(a0, o, 64); a1 += __shfl_xor(a1, o, 64);
            a2 += __shfl_xor(a2, o, 64); a3 += __shfl_xor(a3, o, 64);
            a4 += __shfl_xor(a4, o, 64); a5 += __shfl_xor(a5, o, 64);
        }
        if (lane == 0) {
            const float gl0 = a0, gl1 = a1;
            const float m = fmaxf(gl0, gl1);
            const float e0 = expf(gl0 - m), e1 = expf(gl1 - m);
            const float inv = 1.f / (e0 + e1);
            const float gp0 = e0 * inv, gp1 = e1 * inv;
            const int gidx = (gl1 > gl0) ? 1 : 0;
            const float gw = fmaxf(gp0, gp1);
            float el[4] = { a2, a3, a4, a5 };
            const float me = fmaxf(fmaxf(el[0], el[1]), fmaxf(el[2], el[3]));
            float ep[4]; float se = 0.f;
            #pragma unroll
            for (int i = 0; i < 4; ++i) { ep[i] = expf(el[i] - me); se += ep[i]; }
            const float invs = 1.f / se;
            #pragma unroll
            for (int i = 0; i < 4; ++i) ep[i] *= invs;
            int i0 = 0;
            #pragma unroll
            for (int i = 1; i < 4; ++i) if (ep[i] > ep[i0]) i0 = i;
            int i1 = -1;
            #pragma unroll
            for (int i = 0; i < 4; ++i) { if (i == i0) continue; if (i1 < 0 || ep[i] > ep[i1]) i1 = i; }
            const float w0 = ep[i0], w1 = ep[i1];
            const float sn = w0 + w1 + 1e-7f;
            const float f0 = gw * w0 / sn, f1 = gw * w1 / sn;
            const int ei0 = gidx * GSc + i0, ei1 = gidx * GSc + i1;
            eidx[t * 2] = ei0; eidx[t * 2 + 1] = ei1;
            fw[t * 2] = f0; fw[t * 2 + 1] = f1;
            dmsum[t] = f0 + f1;
            #pragma unroll
            for (int e = 0; e < 8; ++e)
                load8[e] += ((e == ei0) ? f0 : 0.f) + ((e == ei1) ? f1 : 0.f);
            sqg += gl0 * gl0 + gl1 * gl1;
            sqe += el[0] * el[0] + el[1] * el[1] + el[2] * el[2] + el[3] * el[3];
        }
    }
    __shared__ float sh[4][10];
    if (lane == 0) {
        #pragma unroll
        for (int e = 0; e < 8; ++e) sh[wv][e] = load8[e];
        sh[wv][8] = sqg; sh[wv][9] = sqe;
    }
    __syncthreads();
    if (threadIdx.x < 10) {
        rpart[blockIdx.x * 10 + threadIdx.x] =
            sh[0][threadIdx.x] + sh[1][threadIdx.x] + sh[2][threadIdx.x] + sh[3][threadIdx.x];
    }
}

// ---------------- fused LayerNorm + transpose (pre -> adapt_in, adapt_inT) ----
__global__ __launch_bounds__(256) void lntr_k(const float* __restrict__ in,
                                              unsigned short* __restrict__ outn,
                                              unsigned short* __restrict__ outt,
                                              const float* __restrict__ gg,
                                              const float* __restrict__ bb)
{
    __shared__ unsigned short L[64][130];
    const int z = blockIdx.y;
    const int t0 = blockIdx.x * 64;
    const int wv = threadIdx.x >> 6, lane = threadIdx.x & 63;
    const float g0 = gg[lane], g1 = gg[lane + 64];
    const float b0 = bb[lane], b1 = bb[lane + 64];

    #pragma unroll 4
    for (int it = 0; it < 16; ++it) {
        const int row = wv * 16 + it;
        const long long gr = (long long)(z * Sc + t0 + row) * 128;
        const float z0 = in[gr + lane], z1 = in[gr + 64 + lane];
        float s = z0 + z1;
        #pragma unroll
        for (int o = 32; o > 0; o >>= 1) s += __shfl_xor(s, o, 64);
        const float mu = s * (1.f / 128.f);
        const float d0 = z0 - mu, d1 = z1 - mu;
        float v = d0 * d0 + d1 * d1;
        #pragma unroll
        for (int o = 32; o > 0; o >>= 1) v += __shfl_xor(v, o, 64);
        const float r = rsqrtf(v * (1.f / 128.f) + LN_EPSc);
        L[row][lane] = f2b(d0 * r * g0 + b0);
        L[row][lane + 64] = f2b(d1 * r * g1 + b1);
    }
    __syncthreads();
    {
        const int row = threadIdx.x >> 2, seg = (threadIdx.x & 3) * 32;
        #pragma unroll
        for (int j = 0; j < 8; ++j)
            *(us4*)&outn[(long long)(z * Sc + t0 + row) * 128 + seg + j * 4] =
                *(const us4*)&L[row][seg + j * 4];
    }
    {
        const int a = threadIdx.x >> 1, tt0 = (threadIdx.x & 1) * 32;
        #pragma unroll
        for (int j4 = 0; j4 < 8; ++j4) {
            us4 o;
            o.x = L[tt0 + j4 * 4 + 0][a]; o.y = L[tt0 + j4 * 4 + 1][a];
            o.z = L[tt0 + j4 * 4 + 2][a]; o.w = L[tt0 + j4 * 4 + 3][a];
            *(us4*)&outt[(long long)z * Ac * Sc + (long long)a * Sc + t0 + tt0 + j4 * 4] = o;
        }
    }
}

// ---------------- fused 4-way reduce + LayerNorm (post path) ----------------
__global__ __launch_bounds__(64) void redln_k(const float* __restrict__ in,
                                              unsigned short* __restrict__ out,
                                              const float* __restrict__ gg,
                                              const float* __restrict__ bb,
                                              long long pstride)
{
    const int row = blockIdx.x;
    const int lane = threadIdx.x;
    float z0 = 0.f, z1 = 0.f;
    #pragma unroll
    for (int p = 0; p < 4; ++p) {
        z0 += in[p * pstride + (long long)row * 128 + lane];
        z1 += in[p * pstride + (long long)row * 128 + 64 + lane];
    }
    float s = z0 + z1;
    for (int o = 32; o > 0; o >>= 1) s += __shfl_xor(s, o, 64);
    const float mu = s * (1.f / 128.f);
    const float d0 = z0 - mu, d1 = z1 - mu;
    float v = d0 * d0 + d1 * d1;
    for (int o = 32; o > 0; o >>= 1) v += __shfl_xor(v, o, 64);
    const float r = rsqrtf(v * (1.f / 128.f) + LN_EPSc);
    out[(long long)row * 128 + lane] = f2b(d0 * r * gg[lane] + bb[lane]);
    out[(long long)row * 128 + 64 + lane] = f2b(d1 * r * gg[lane + 64] + bb[lane + 64]);
}

// ---------------- loss reduce over RBLK partial rows ----------------
__global__ __launch_bounds__(512) void loss_k(const float* __restrict__ rpart,
                                              float* __restrict__ out_loss)
{
    const int tid = threadIdx.x;
    const int lane = tid & 63, wv = tid >> 6;
    float v[10];
    #pragma unroll
    for (int c = 0; c < 10; ++c) v[c] = rpart[tid * 10 + c];
    #pragma unroll
    for (int o = 32; o > 0; o >>= 1)
        #pragma unroll
        for (int c = 0; c < 10; ++c) v[c] += __shfl_xor(v[c], o, 64);
    __shared__ float sh[8][10];
    if (lane == 0) {
        #pragma unroll
        for (int c = 0; c < 10; ++c) sh[wv][c] = v[c];
    }
    __syncthreads();
    if (tid == 0) {
        float load[8]; float sqg = 0.f, sqe = 0.f;
        #pragma unroll
        for (int e = 0; e < 8; ++e) load[e] = 0.f;
        for (int wvi = 0; wvi < 8; ++wvi) {
            #pragma unroll
            for (int e = 0; e < 8; ++e) load[e] += sh[wvi][e];
            sqg += sh[wvi][8]; sqe += sh[wvi][9];
        }
        float s = 0.f;
        for (int e = 0; e < Ec; ++e) s += load[e];
        const float tgt = s / (float)Ec;
        float var = 0.f;
        for (int e = 0; e < Ec; ++e) { const float d = load[e] - tgt; var += d * d; }
        var /= (float)Ec;
        const float l = var + sqg / (float)(Nc * Gc) + sqe / (float)(Nc * GSc);
        *out_loss = 0.001f * l;
    }
}

// ---------------- combine: h2[t] = sum_slot fw * LN_e(h_dense[e][t]) ----------------
__global__ __launch_bounds__(128) void combine_k(const float* __restrict__ h_dense,
                                                 const float* __restrict__ ln_g_e,
                                                 const float* __restrict__ ln_b_e,
                                                 const int* __restrict__ eidx,
                                                 const float* __restrict__ fw,
                                                 unsigned short* __restrict__ h2)
{
    const int t = blockIdx.x;
    const int tid = threadIdx.x;
    __shared__ float red[2];

    float acc = 0.f;
    #pragma unroll
    for (int slot = 0; slot < 2; ++slot) {
        const int e = eidx[t * 2 + slot];
        const float w = fw[t * 2 + slot];
        const float h = h_dense[((long long)e * Nc + t) * 128 + tid];
        float v = h;
        for (int o = 32; o > 0; o >>= 1) v += __shfl_down(v, o, 64);
        if ((tid & 63) == 0) red[tid >> 6] = v;
        __syncthreads();
        const float mu = (red[0] + red[1]) * (1.f / 128.f);
        __syncthreads();
        const float d = h - mu;
        v = d * d;
        for (int o = 32; o > 0; o >>= 1) v += __shfl_down(v, o, 64);
        if ((tid & 63) == 0) red[tid >> 6] = v;
        __syncthreads();
        const float var = (red[0] + red[1]) * (1.f / 128.f);
        __syncthreads();
        acc += w * (d * rsqrtf(var + LN_EPSc) * ln_g_e[e * 128 + tid] + ln_b_e[e * 128 + tid]);
    }
    h2[(long long)t * 128 + tid] = f2b(acc);
}

// =====================================================================
extern "C" void kernel_launch(void* const* d_in, const int* in_sizes, int n_in,
                              void* d_out, int out_size, void* d_ws, size_t ws_size,
                              hipStream_t stream)
{
    const float* x       = (const float*)d_in[0];
    const float* W_up    = (const float*)d_in[1];
    const float* W_gate  = (const float*)d_in[2];
    const float* W_down  = (const float*)d_in[3];
    const float* W_pre   = (const float*)d_in[4];
    const float* W_post  = (const float*)d_in[5];
    const float* ln_g    = (const float*)d_in[6];
    const float* ln_b    = (const float*)d_in[7];
    const float* W_aproj = (const float*)d_in[8];
    const float* A_exp   = (const float*)d_in[9];
    const float* ln_g_e  = (const float*)d_in[10];
    const float* ln_b_e  = (const float*)d_in[11];
    const float* W_eproj = (const float*)d_in[12];
    const float* W_oproj = (const float*)d_in[13];
    const float* W_rg    = (const float*)d_in[14];
    const float* W_re    = (const float*)d_in[15];

    float* out = (float*)d_out;

    // ---- workspace carve ----
    char* p = (char*)d_ws;
    auto alloc = [&](size_t bytes) { void* r = (void*)p; p += (bytes + 255) & ~(size_t)255; return r; };
    float* pre      = (float*)alloc((size_t)Nc * Ac * 4);
    float* h_dense  = (float*)alloc((size_t)Ec * Nc * Ac * 4);   // scratch: wprepP / postP / h_dense / adaptP
    float* rpart    = (float*)alloc((size_t)RBLK * 10 * 4);
    float* fw       = (float*)alloc((size_t)Nc * 2 * 4);
    float* dmsum    = (float*)alloc((size_t)Nc * 4);
    int*   eidx     = (int*)alloc((size_t)Nc * 2 * 4);
    unsigned short* xb      = (unsigned short*)alloc((size_t)Nc * Dc * 2);
    unsigned short* Wcat_b  = (unsigned short*)alloc((size_t)(2 * Hc + Ac) * Dc * 2);
    unsigned short* Wd_b    = (unsigned short*)alloc((size_t)Dc * Hc * 2);
    unsigned short* Wop_b   = (unsigned short*)alloc((size_t)Dc * Hc * 2);
    unsigned short* Wpost_b = (unsigned short*)alloc((size_t)Ac * Hc * 2);
    unsigned short* WapT_b  = (unsigned short*)alloc((size_t)Ac * Hc * 2);
    unsigned short* WepT_b  = (unsigned short*)alloc((size_t)Ac * Hc * 2);
    unsigned short* Wdap_b  = (unsigned short*)alloc((size_t)Dc * Ac * 2);
    unsigned short* Wopep_b = (unsigned short*)alloc((size_t)Dc * Ac * 2);
    unsigned short* Aexp_b  = (unsigned short*)alloc((size_t)Ec * Ac * Ac * 2);
    unsigned short* pre_b   = (unsigned short*)alloc((size_t)Nc * Ac * 2);
    unsigned short* hidden  = (unsigned short*)alloc((size_t)Nc * Hc * 2);
    unsigned short* adapt_in  = (unsigned short*)alloc((size_t)Nc * Ac * 2);
    unsigned short* adapt_inT = (unsigned short*)alloc((size_t)Nc * Ac * 2);
    unsigned short* adapt_out = (unsigned short*)alloc((size_t)Nc * Ac * 2);
    unsigned short* adaptb    = (unsigned short*)alloc((size_t)Nc * Ac * 2);
    unsigned short* h2        = (unsigned short*)alloc((size_t)Nc * Ac * 2);

    float* wprepP = h_dense;   // [4 split][2 pair][1024*128] f32
    float* postP  = h_dense;   // [4][4096*128] f32
    float* adaptP = h_dense;   // [8][2][2048*128] f32

    // ---- weight prep (standalone) + router (standalone slim) ----
    PrepArgs pa;
    pa.csrc[0] = W_down;  pa.cdst[0] = Wd_b;    pa.cn4[0] = Dc * Hc / 4;
    pa.csrc[1] = W_oproj; pa.cdst[1] = Wop_b;   pa.cn4[1] = Dc * Hc / 4;
    pa.csrc[2] = W_post;  pa.cdst[2] = Wpost_b; pa.cn4[2] = Ac * Hc / 4;
    pa.csrc[3] = A_exp;   pa.cdst[3] = Aexp_b;  pa.cn4[3] = Ec * Ac * Ac / 4;
    pa.Wg = W_gate; pa.Wu = W_up; pa.Wpre = W_pre; pa.Wcat = Wcat_b;
    pa.tin0 = W_aproj; pa.tin1 = W_eproj; pa.tout0 = WapT_b; pa.tout1 = WepT_b;
    prep_k<<<dim3(64, 6), 256, 0, stream>>>(pa);
    router_k<<<RBLK, 256, 0, stream>>>(x, W_rg, W_re, eidx, fw, dmsum, rpart, xb);
    loss_k<<<1, 512, 0, stream>>>(rpart, out + (size_t)Nc * Dc);

    // ---- Wdap/Wopep split-K (4x512), z=(pair,split), then alpha=0.1 reduce ----
    mgemm64<<<dim3(2, 8, 8), 256, 0, stream>>>(Wd_b, WapT_b, wprepP, Ac, 512, Hc, Hc,
        2,
        (long long)Dc * Hc, (long long)Ac * Hc, (long long)Dc * Ac,
        512, 512, (long long)2 * Dc * Ac);
    reduce_k<4, 1><<<256, 256, 0, stream>>>(wprepP, Wdap_b,
        (long long)2 * Dc * Ac, 2 * Dc * Ac / 4, 0.1f);

    // ---- fused gate+up+pre (BK=64, PR=8 x PC=3 panel swizzle) ----
    mgemm<9><<<dim3(33, 32), 256, 0, stream>>>(xb, Wcat_b, hidden, 2 * Hc + Ac, Dc, Dc, Dc,
        8, 3, 0.f, pre, pre_b, 0, 0, 0);
    lntr_k<<<dim3(Sc / 64, Bc), 256, 0, stream>>>(pre, adapt_in, adapt_inT, ln_g, ln_b);

    // ---- post split-K via mgemm (single 128-wide x-tile, z=4 K-splits) ----
    mgemm<0><<<dim3(1, 32, 4), 256, 0, stream>>>(hidden, Wpost_b, postP, Ac, 512, Hc, Hc,
        4, 1, 0.f, nullptr, nullptr, 512, 512, (long long)Nc * Ac);
    redln_k<<<Nc, 64, 0, stream>>>(postP, adapt_out, ln_g, ln_b, (long long)Nc * Ac);

    // ---- dense expert adapter via mgemm: h_dense[e] = pre_b @ A_exp[e]^T ----
    mgemm<0><<<dim3(1, 32, Ec), 256, 0, stream>>>(pre_b, Aexp_b, h_dense, Ac, Ac, Ac, Ac,
        4, 1, 0.f, nullptr, nullptr, 0, (long long)Ac * Ac, (long long)Nc * Ac);
    combine_k<<<Nc, 128, 0, stream>>>(h_dense, ln_g_e, ln_b_e, eidx, fw, h2);

    // ---- fused aw+adapt (direct-global fragments, QBLK=64, 512 blocks) ----
    fadapt_k<<<dim3(8, 32, 2), 256, 0, stream>>>(adapt_in, adapt_out, adapt_inT, adaptP);
    reduce_k<8, 1><<<512, 256, 0, stream>>>(adaptP, adaptb,
        (long long)2 * Sc * Ac, 2 * Sc * Ac / 4, 1.f);

    // ---- final fused (BK=64, PR=4 x PC=4 panel swizzle) ----
    final_k<<<dim3(Dc / 64, Nc / 128), 256, 0, stream>>>(
        hidden, Wd_b, adaptb, Wdap_b, h2, Wopep_b, dmsum, out);
}

// Round 18
// 189.747 us; speedup vs baseline: 1.0575x; 1.0575x over previous
//
#include <hip/hip_runtime.h>
#include <hip/hip_bf16.h>
#include <math.h>

static constexpr int Bc = 2;
static constexpr int Sc = 2048;
static constexpr int Dc = 1024;
static constexpr int Hc = 2048;
static constexpr int Ac = 128;
static constexpr int Ec = 8;
static constexpr int GSc = 4;
static constexpr int Gc = 2;
static constexpr int Nc = Bc * Sc;   // 4096 tokens
static constexpr float LN_EPSc = 1e-5f;
static constexpr int RBLK = 512;     // router blocks

typedef __attribute__((ext_vector_type(8))) short bf16x8;
typedef __attribute__((ext_vector_type(4))) float f32x4;
typedef __attribute__((ext_vector_type(4))) unsigned short us4;

__device__ __forceinline__ unsigned short f2b(float f) {
    union { float f; unsigned u; } v; v.f = f;
    return (unsigned short)((v.u + 0x7FFFu + ((v.u >> 16) & 1u)) >> 16);
}
__device__ __forceinline__ float b2f(unsigned short h) {
    union { unsigned u; float f; } v; v.u = (unsigned)h << 16; return v.f;
}
__device__ __forceinline__ float fsilu(float x) {
    return x / (1.f + __expf(-x));
}

#define GLOAD16(g, l) __builtin_amdgcn_global_load_lds( \
    (const __attribute__((address_space(1))) void*)(g), \
    (__attribute__((address_space(3))) void*)(l), 16, 0, 0)

// 2-D L2-panel swizzle: XCD k executes a contiguous chunk of tile-order; order
// tiles in PR-row x PC-col panels so each chunk's working set fits per-XCD L2.
__device__ __forceinline__ void panel_swizzle(int gx, int gy, int PR, int PC,
                                              int& bx, int& by)
{
    const int nwg = gx * gy;
    const int flat = blockIdx.y * gx + blockIdx.x;
    const int ord = (flat & 7) * (nwg >> 3) + (flat >> 3);   // XCD chunking
    const int srw = gx * PR;            // tiles per super-row
    const int sr = ord / srw;
    int rem = ord % srw;
    const int pi = rem / (PR * PC);
    rem %= (PR * PC);
    by = sr * PR + rem / PC;
    bx = pi * PC + rem % PC;
}

// ---------------- bf16 MFMA GEMM, 128x128 tile, BK=64, bank-swizzled ----------
// (round-9 proven structure). EPI 9 = gateup paired silu + pre side-channel.
// EPI 0 = f32 store (also used split-K via blockIdx.z strides).
template<int EPI>
__global__ __launch_bounds__(256, 4) void mgemm(
    const unsigned short* __restrict__ Ag, const unsigned short* __restrict__ Bg,
    void* __restrict__ Cg, int N, int K, int lda, int ldb, int PR, int PC, float alpha,
    float* __restrict__ aux, void* __restrict__ aux2,
    long long sA, long long sB, long long sC)
{
    __shared__ unsigned short As[128 * 64];
    __shared__ unsigned short Bs[128 * 64];
    const unsigned short* A = Ag + (long long)blockIdx.z * sA;
    const unsigned short* B = Bg + (long long)blockIdx.z * sB;
    float* fC = (float*)Cg + (long long)blockIdx.z * sC;
    unsigned short* usC = (unsigned short*)Cg + (long long)blockIdx.z * sC;

    int bx, by;
    panel_swizzle(gridDim.x, gridDim.y, PR, PC, bx, by);
    const int bm = by * 128, bn = bx * 128;

    const int tid = threadIdx.x;
    const int w = tid >> 6, l = tid & 63;
    const int wm = (w >> 1) * 64, wn = (w & 1) * 64;
    const int fr = l & 15, g = l >> 4;

    const f32x4 zero = { 0.f, 0.f, 0.f, 0.f };
    f32x4 acc[4][4];
    #pragma unroll
    for (int i = 0; i < 4; ++i)
        #pragma unroll
        for (int j = 0; j < 4; ++j) acc[i][j] = zero;

    for (int k0 = 0; k0 < K; k0 += 64) {
        #pragma unroll
        for (int p = 0; p < 4; ++p) {
            const int c = p * 256 + tid;
            const int row = c >> 3;
            const int gch = (c & 7) ^ ((c >> 4) & 7);
            GLOAD16(A + (long long)(bm + row) * lda + k0 + gch * 8, &As[c * 8]);
            GLOAD16(B + (long long)(bn + row) * ldb + k0 + gch * 8, &Bs[c * 8]);
        }
        __syncthreads();
        #pragma unroll
        for (int h = 0; h < 2; ++h) {
            bf16x8 af[4], bfv[4];
            #pragma unroll
            for (int i = 0; i < 4; ++i) {
                const int ra = wm + i * 16 + fr;
                af[i]  = *(const bf16x8*)&As[ra * 64 + ((h * 4 + g) ^ ((ra >> 1) & 7)) * 8];
                const int rb = wn + i * 16 + fr;
                bfv[i] = *(const bf16x8*)&Bs[rb * 64 + ((h * 4 + g) ^ ((rb >> 1) & 7)) * 8];
            }
            #pragma unroll
            for (int i = 0; i < 4; ++i)
                #pragma unroll
                for (int j = 0; j < 4; ++j)
                    acc[i][j] = __builtin_amdgcn_mfma_f32_16x16x32_bf16(af[i], bfv[j], acc[i][j], 0, 0, 0);
        }
        __syncthreads();
    }

    if (EPI == 9) {
        if (bn < 2 * Hc) {
            #pragma unroll
            for (int mi = 0; mi < 4; ++mi) {
                #pragma unroll
                for (int j = 0; j < 2; ++j) {
                    #pragma unroll
                    for (int jr = 0; jr < 4; ++jr) {
                        const long long row = bm + wm + mi * 16 + g * 4 + jr;
                        const long long colh = ((bn + wn) >> 1) + j * 16 + fr;
                        const float gv = acc[mi][2 * j][jr];
                        const float uv = acc[mi][2 * j + 1][jr];
                        usC[row * Hc + colh] = f2b(fsilu(gv) * uv);
                    }
                }
            }
        } else {
            unsigned short* preb = (unsigned short*)aux2;
            #pragma unroll
            for (int mi = 0; mi < 4; ++mi) {
                #pragma unroll
                for (int ni = 0; ni < 4; ++ni) {
                    #pragma unroll
                    for (int jr = 0; jr < 4; ++jr) {
                        const long long row = bm + wm + mi * 16 + g * 4 + jr;
                        const int lc = wn + ni * 16 + fr;
                        const float v = acc[mi][ni][jr];
                        aux[row * Ac + lc] = v;
                        preb[row * Ac + lc] = f2b(v);
                    }
                }
            }
        }
    } else {
        #pragma unroll
        for (int mi = 0; mi < 4; ++mi)
            #pragma unroll
            for (int ni = 0; ni < 4; ++ni)
                #pragma unroll
                for (int jr = 0; jr < 4; ++jr) {
                    const long long row = bm + wm + mi * 16 + g * 4 + jr;
                    const long long col = bn + wn + ni * 16 + fr;
                    const long long idx = row * (long long)N + col;
                    const float v = acc[mi][ni][jr];
                    if (EPI == 0) fC[idx] = v;
                    else usC[idx] = f2b(alpha * v);
                }
    }
}

// ---------------- bf16 MFMA GEMM, 128x64 tile (f32 out), BK=32, 2-axis z -----
// (used only for the Wdap/Wopep split-K prep now)
__global__ __launch_bounds__(256, 2) void mgemm64(
    const unsigned short* __restrict__ Ag, const unsigned short* __restrict__ Bg,
    float* __restrict__ Cg, int N, int K, int lda, int ldb, int zmod,
    long long sA1, long long sB1, long long sC1,
    long long sA2, long long sB2, long long sC2)
{
    __shared__ unsigned short As[128 * 32];
    __shared__ unsigned short Bs[64 * 32];
    const int z1 = blockIdx.z % zmod, z2 = blockIdx.z / zmod;
    const unsigned short* A = Ag + (long long)z1 * sA1 + (long long)z2 * sA2;
    const unsigned short* B = Bg + (long long)z1 * sB1 + (long long)z2 * sB2;
    float* fC = Cg + (long long)z1 * sC1 + (long long)z2 * sC2;

    const int nwg = gridDim.x * gridDim.y;
    const int flat = blockIdx.y * gridDim.x + blockIdx.x;
    const int swz = (flat & 7) * (nwg >> 3) + (flat >> 3);
    const int bx = swz % gridDim.x, by = swz / gridDim.x;
    const int bm = by * 128, bn = bx * 64;

    const int tid = threadIdx.x;
    const int w = tid >> 6, l = tid & 63;
    const int wm = (w >> 1) * 64, wn = (w & 1) * 32;
    const int fr = l & 15, g = l >> 4;

    const f32x4 zero = { 0.f, 0.f, 0.f, 0.f };
    f32x4 acc[4][2];
    #pragma unroll
    for (int i = 0; i < 4; ++i)
        #pragma unroll
        for (int j = 0; j < 2; ++j) acc[i][j] = zero;

    for (int k0 = 0; k0 < K; k0 += 32) {
        #pragma unroll
        for (int p = 0; p < 2; ++p) {
            const int c = p * 256 + tid;
            GLOAD16(A + (long long)(bm + (c >> 2)) * lda + k0 + (c & 3) * 8, &As[c * 8]);
        }
        GLOAD16(B + (long long)(bn + (tid >> 2)) * ldb + k0 + (tid & 3) * 8, &Bs[tid * 8]);
        __syncthreads();
        bf16x8 af[4], bfv[2];
        #pragma unroll
        for (int i = 0; i < 4; ++i)
            af[i]  = *(const bf16x8*)&As[(wm + i * 16 + fr) * 32 + g * 8];
        #pragma unroll
        for (int j = 0; j < 2; ++j)
            bfv[j] = *(const bf16x8*)&Bs[(wn + j * 16 + fr) * 32 + g * 8];
        #pragma unroll
        for (int i = 0; i < 4; ++i)
            #pragma unroll
            for (int j = 0; j < 2; ++j)
                acc[i][j] = __builtin_amdgcn_mfma_f32_16x16x32_bf16(af[i], bfv[j], acc[i][j], 0, 0, 0);
        __syncthreads();
    }

    #pragma unroll
    for (int mi = 0; mi < 4; ++mi)
        #pragma unroll
        for (int ni = 0; ni < 2; ++ni)
            #pragma unroll
            for (int jr = 0; jr < 4; ++jr) {
                const long long row = bm + wm + mi * 16 + g * 4 + jr;
                const long long col = bn + wn + ni * 16 + fr;
                fC[row * (long long)N + col] = acc[mi][ni][jr];
            }
}

// ---------------- fused aw+adapt: direct-global fragments, QBLK=64 ------------
// (round-13 exact)
__global__ __launch_bounds__(256, 2) void fadapt_k(
    const unsigned short* __restrict__ adapt_in,
    const unsigned short* __restrict__ adapt_out,
    const unsigned short* __restrict__ adapt_inT,
    float* __restrict__ partial)
{
    __shared__ unsigned short P_lds[4 * 64 * 32];   // [ks][qrow][chunk-swizzled]

    const int b = blockIdx.z;
    const int q0 = blockIdx.y * 64;
    const int t0 = blockIdx.x * 256;

    const unsigned short* Qg = adapt_in + (long long)b * Sc * Ac;
    const unsigned short* Kg = adapt_out + (long long)b * Sc * Ac;
    const unsigned short* Vt = adapt_inT + (long long)b * Ac * Sc;

    const int tid = threadIdx.x;
    const int w = tid >> 6, l = tid & 63;
    const int wm = (w >> 1) * 32, wn = (w & 1) * 64;
    const int fr = l & 15, g = l >> 4;

    bf16x8 qf[2][4];
    #pragma unroll
    for (int i = 0; i < 2; ++i) {
        const long long ra = q0 + wm + i * 16 + fr;
        #pragma unroll
        for (int ks = 0; ks < 4; ++ks)
            qf[i][ks] = *(const bf16x8*)&Qg[ra * Ac + ks * 32 + g * 8];
    }

    const f32x4 zero = { 0.f, 0.f, 0.f, 0.f };
    f32x4 acc[2][4];
    #pragma unroll
    for (int i = 0; i < 2; ++i)
        #pragma unroll
        for (int j = 0; j < 4; ++j) acc[i][j] = zero;

    #pragma unroll 1
    for (int ts = 0; ts < 2; ++ts) {
        const int t1 = t0 + ts * 128;
        f32x4 sacc[2][4];
        #pragma unroll
        for (int i = 0; i < 2; ++i)
            #pragma unroll
            for (int j = 0; j < 4; ++j) sacc[i][j] = zero;
        #pragma unroll
        for (int ks = 0; ks < 4; ++ks) {
            bf16x8 bfv[4];
            #pragma unroll
            for (int j = 0; j < 4; ++j) {
                const long long rb = t1 + wn + j * 16 + fr;
                bfv[j] = *(const bf16x8*)&Kg[rb * Ac + ks * 32 + g * 8];
            }
            #pragma unroll
            for (int i = 0; i < 2; ++i)
                #pragma unroll
                for (int j = 0; j < 4; ++j)
                    sacc[i][j] = __builtin_amdgcn_mfma_f32_16x16x32_bf16(qf[i][ks], bfv[j], sacc[i][j], 0, 0, 0);
        }
        __syncthreads();
        #pragma unroll
        for (int mi = 0; mi < 2; ++mi) {
            #pragma unroll
            for (int ni = 0; ni < 4; ++ni) {
                const int t = wn + ni * 16 + fr;
                const int tl = t & 31;
                const int kbase = (t >> 5) * 2048;
                #pragma unroll
                for (int jr = 0; jr < 4; ++jr) {
                    const int row = wm + mi * 16 + g * 4 + jr;
                    float v = sacc[mi][ni][jr];
                    v = fminf(fmaxf(v, -5.f), 5.f);
                    const int pos = (((tl >> 3) ^ ((row >> 1) & 3)) << 3) + (tl & 7);
                    P_lds[kbase + row * 32 + pos] = f2b(fsilu(v));
                }
            }
        }
        __syncthreads();
        #pragma unroll
        for (int ks = 0; ks < 4; ++ks) {
            bf16x8 af[2], bfv[4];
            #pragma unroll
            for (int i = 0; i < 2; ++i) {
                const int ra = wm + i * 16 + fr;
                af[i] = *(const bf16x8*)&P_lds[ks * 2048 + ra * 32 + (g ^ ((ra >> 1) & 3)) * 8];
            }
            #pragma unroll
            for (int j = 0; j < 4; ++j) {
                const long long rb = wn + j * 16 + fr;
                bfv[j] = *(const bf16x8*)&Vt[rb * Sc + t1 + ks * 32 + g * 8];
            }
            #pragma unroll
            for (int i = 0; i < 2; ++i)
                #pragma unroll
                for (int j = 0; j < 4; ++j)
                    acc[i][j] = __builtin_amdgcn_mfma_f32_16x16x32_bf16(af[i], bfv[j], acc[i][j], 0, 0, 0);
        }
    }

    float* op = partial + ((long long)blockIdx.x * Bc + b) * Sc * Ac;
    #pragma unroll
    for (int mi = 0; mi < 2; ++mi)
        #pragma unroll
        for (int ni = 0; ni < 4; ++ni)
            #pragma unroll
            for (int jr = 0; jr < 4; ++jr) {
                const long long row = q0 + wm + mi * 16 + g * 4 + jr;
                const long long col = wn + ni * 16 + fr;
                op[row * Ac + col] = acc[mi][ni][jr];
            }
}

// ---------------- final fused 3-phase GEMM, 128x64 tile, BK=64, swizzled ------
__global__ __launch_bounds__(256, 2) void final_k(
    const unsigned short* __restrict__ hidden, const unsigned short* __restrict__ Wd,
    const unsigned short* __restrict__ adaptb, const unsigned short* __restrict__ Wdap,
    const unsigned short* __restrict__ h2v, const unsigned short* __restrict__ Wopep,
    const float* __restrict__ dmsum, float* __restrict__ out)
{
    __shared__ unsigned short As[128 * 64];
    __shared__ unsigned short Bs[64 * 64];

    int bx, by;
    panel_swizzle(gridDim.x, gridDim.y, 4, 4, bx, by);
    const int bm = by * 128, bn = bx * 64;

    const int tid = threadIdx.x;
    const int w = tid >> 6, l = tid & 63;
    const int wm = (w >> 1) * 64, wn = (w & 1) * 32;
    const int fr = l & 15, g = l >> 4;

    const f32x4 zero = { 0.f, 0.f, 0.f, 0.f };
    f32x4 acc[4][2];
    #pragma unroll
    for (int i = 0; i < 4; ++i)
        #pragma unroll
        for (int j = 0; j < 2; ++j) acc[i][j] = zero;

    const unsigned short* Ap[3] = { hidden, adaptb, h2v };
    const unsigned short* Bp[3] = { Wd, Wdap, Wopep };
    const int Ks[3] = { Hc, Ac, Ac };

    #pragma unroll 1
    for (int ph = 0; ph < 3; ++ph) {
        if (ph == 2) {
            #pragma unroll
            for (int mi = 0; mi < 4; ++mi)
                #pragma unroll
                for (int jr = 0; jr < 4; ++jr) {
                    const float rs = dmsum[bm + wm + mi * 16 + g * 4 + jr];
                    #pragma unroll
                    for (int ni = 0; ni < 2; ++ni) acc[mi][ni][jr] *= rs;
                }
        }
        const unsigned short* A = Ap[ph];
        const unsigned short* B = Bp[ph];
        const int K = Ks[ph];
        for (int k0 = 0; k0 < K; k0 += 64) {
            #pragma unroll
            for (int p = 0; p < 4; ++p) {
                const int c = p * 256 + tid;
                const int row = c >> 3;
                const int gch = (c & 7) ^ ((c >> 4) & 7);
                GLOAD16(A + (long long)(bm + row) * K + k0 + gch * 8, &As[c * 8]);
            }
            #pragma unroll
            for (int p = 0; p < 2; ++p) {
                const int c = p * 256 + tid;
                const int row = c >> 3;
                const int gch = (c & 7) ^ ((c >> 4) & 7);
                GLOAD16(B + (long long)(bn + row) * K + k0 + gch * 8, &Bs[c * 8]);
            }
            __syncthreads();
            #pragma unroll
            for (int h = 0; h < 2; ++h) {
                bf16x8 af[4], bfv[2];
                #pragma unroll
                for (int i = 0; i < 4; ++i) {
                    const int ra = wm + i * 16 + fr;
                    af[i]  = *(const bf16x8*)&As[ra * 64 + ((h * 4 + g) ^ ((ra >> 1) & 7)) * 8];
                }
                #pragma unroll
                for (int j = 0; j < 2; ++j) {
                    const int rb = wn + j * 16 + fr;
                    bfv[j] = *(const bf16x8*)&Bs[rb * 64 + ((h * 4 + g) ^ ((rb >> 1) & 7)) * 8];
                }
                #pragma unroll
                for (int i = 0; i < 4; ++i)
                    #pragma unroll
                    for (int j = 0; j < 2; ++j)
                        acc[i][j] = __builtin_amdgcn_mfma_f32_16x16x32_bf16(af[i], bfv[j], acc[i][j], 0, 0, 0);
            }
            __syncthreads();
        }
    }

    #pragma unroll
    for (int mi = 0; mi < 4; ++mi)
        #pragma unroll
        for (int ni = 0; ni < 2; ++ni)
            #pragma unroll
            for (int jr = 0; jr < 4; ++jr) {
                const long long row = bm + wm + mi * 16 + g * 4 + jr;
                const long long col = bn + wn + ni * 16 + fr;
                out[row * (long long)Dc + col] = acc[mi][ni][jr];
            }
}

// ---------------- partial-sum reduce: out = alpha * sum_p in[p*stride + i] ----
template<int NP, int BF>
__global__ __launch_bounds__(256) void reduce_k(const float* __restrict__ in,
                                                void* __restrict__ outp,
                                                long long pstride, int n4, float alpha)
{
    for (int i = blockIdx.x * 256 + threadIdx.x; i < n4; i += gridDim.x * 256) {
        float4 s = ((const float4*)in)[i];
        #pragma unroll
        for (int p = 1; p < NP; ++p) {
            const float4 v = ((const float4*)(in + (long long)p * pstride))[i];
            s.x += v.x; s.y += v.y; s.z += v.z; s.w += v.w;
        }
        s.x *= alpha; s.y *= alpha; s.z *= alpha; s.w *= alpha;
        if (BF) {
            us4 o = { f2b(s.x), f2b(s.y), f2b(s.z), f2b(s.w) };
            ((us4*)outp)[i] = o;
        } else {
            ((float4*)outp)[i] = s;
        }
    }
}

// ---------------- merged prep + router kernel --------------------------------
// blocks [0,384): weight prep (casts / gate-up interleave / transposes)
// blocks [384,896): router (also emits xb bf16 cast of x)
struct PrepArgs {
    const float* csrc[4]; unsigned short* cdst[4]; int cn4[4];
    const float* Wg; const float* Wu; const float* Wpre; unsigned short* Wcat;
    const float* tin0; const float* tin1; unsigned short* tout0; unsigned short* tout1;
};
__global__ __launch_bounds__(256) void preprt_k(PrepArgs a,
    const float* __restrict__ x, const float* __restrict__ W_rg,
    const float* __restrict__ W_re, int* __restrict__ eidx,
    float* __restrict__ fw, float* __restrict__ dmsum,
    float* __restrict__ rpart, unsigned short* __restrict__ xb)
{
    __shared__ float T[64][68];
    __shared__ float sh[4][10];
    const int tid = threadIdx.x;

    if (blockIdx.x < 384) {
        const int bx = blockIdx.x & 63;     // 64 x-blocks
        const int y = blockIdx.x >> 6;      // 6 lanes
        if (y < 4) {
            const float4* s = (const float4*)a.csrc[y];
            us4* d = (us4*)a.cdst[y];
            const int n = a.cn4[y];
            for (int i = bx * 256 + tid; i < n; i += 64 * 256) {
                const float4 v = s[i];
                us4 o;
                o.x = f2b(v.x); o.y = f2b(v.y); o.z = f2b(v.z); o.w = f2b(v.w);
                d[i] = o;
            }
        } else if (y == 4) {
            const int total = (2 * Hc + Ac) * 256;
            for (int u = bx * 256 + tid; u < total; u += 64 * 256) {
                const int r = u >> 8, t = u & 255;
                const float* src; int srcrow;
                if (r < 2 * Hc) {
                    const int b = r >> 5, wq = r & 31;
                    src = (wq < 16) ? a.Wg : a.Wu;
                    srcrow = b * 16 + (wq & 15);
                } else {
                    src = a.Wpre;
                    srcrow = r - 2 * Hc;
                }
                const float4 v = ((const float4*)(src + (long long)srcrow * Dc))[t];
                us4 o;
                o.x = f2b(v.x); o.y = f2b(v.y); o.z = f2b(v.z); o.w = f2b(v.w);
                ((us4*)(a.Wcat + (long long)r * Dc))[t] = o;
            }
        } else {
            const int rr = tid >> 4, cc = (tid & 15) * 4;
            for (int tb = bx; tb < 128; tb += 64) {
                const int z = tb >> 6, rem = tb & 63;
                const int a0 = (rem >> 5) * 64, t0 = (rem & 31) * 64;
                const float* in = z ? a.tin1 : a.tin0;
                unsigned short* outp = z ? a.tout1 : a.tout0;
                __syncthreads();
                #pragma unroll
                for (int p = 0; p < 4; ++p) {
                    const int row = p * 16 + rr;
                    *(float4*)&T[row][cc] = *(const float4*)&in[(long long)(t0 + row) * Ac + a0 + cc];
                }
                __syncthreads();
                #pragma unroll
                for (int p = 0; p < 4; ++p) {
                    const int ar = p * 16 + rr;
                    us4 o;
                    o.x = f2b(T[cc + 0][ar]); o.y = f2b(T[cc + 1][ar]);
                    o.z = f2b(T[cc + 2][ar]); o.w = f2b(T[cc + 3][ar]);
                    *(us4*)&outp[(long long)(a0 + ar) * Hc + t0 + cc] = o;
                }
            }
        }
        return;
    }

    // ---- router path ----
    const int rb = blockIdx.x - 384;
    const int wv = tid >> 6;
    const int lane = tid & 63;
    float load8[8] = {0.f, 0.f, 0.f, 0.f, 0.f, 0.f, 0.f, 0.f};
    float sqg = 0.f, sqe = 0.f;

    #pragma unroll
    for (int it = 0; it < 2; ++it) {
        const int t = rb * 8 + wv * 2 + it;
        const float* xr = x + (long long)t * Dc;
        float a0 = 0, a1 = 0, a2 = 0, a3 = 0, a4 = 0, a5 = 0;
        #pragma unroll
        for (int j = 0; j < 16; ++j) {
            const int d = lane + 64 * j;
            const float xv = xr[d];
            xb[(long long)t * Dc + d] = f2b(xv);
            a0 += xv * W_rg[d];          a1 += xv * W_rg[Dc + d];
            a2 += xv * W_re[d];          a3 += xv * W_re[Dc + d];
            a4 += xv * W_re[2 * Dc + d]; a5 += xv * W_re[3 * Dc + d];
        }
        #pragma unroll
        for (int o = 32; o > 0; o >>= 1) {
            a0 += __shfl_xor(a0, o, 64); a1 += __shfl_xor(a1, o, 64);
            a2 += __shfl_xor(a2, o, 64); a3 += __shfl_xor(a3, o, 64);
            a4 += __shfl_xor(a4, o, 64); a5 += __shfl_xor(a5, o, 64);
        }
        if (lane == 0) {
            const float gl0 = a0, gl1 = a1;
            const float m = fmaxf(gl0, gl1);
            const float e0 = expf(gl0 - m), e1 = expf(gl1 - m);
            const float inv = 1.f / (e0 + e1);
            const float gp0 = e0 * inv, gp1 = e1 * inv;
            const int gidx = (gl1 > gl0) ? 1 : 0;
            const float gw = fmaxf(gp0, gp1);
            float el[4] = { a2, a3, a4, a5 };
            const float me = fmaxf(fmaxf(el[0], el[1]), fmaxf(el[2], el[3]));
            float ep[4]; float se = 0.f;
            #pragma unroll
            for (int i = 0; i < 4; ++i) { ep[i] = expf(el[i] - me); se += ep[i]; }
            const float invs = 1.f / se;
            #pragma unroll
            for (int i = 0; i < 4; ++i) ep[i] *= invs;
            int i0 = 0;
            #pragma unroll
            for (int i = 1; i < 4; ++i) if (ep[i] > ep[i0]) i0 = i;
            int i1 = -1;
            #pragma unroll
            for (int i = 0; i < 4; ++i) { if (i == i0) continue; if (i1 < 0 || ep[i] > ep[i1]) i1 = i; }
            const float w0 = ep[i0], w1 = ep[i1];
            const float sn = w0 + w1 + 1e-7f;
            const float f0 = gw * w0 / sn, f1 = gw * w1 / sn;
            const int ei0 = gidx * GSc + i0, ei1 = gidx * GSc + i1;
            eidx[t * 2] = ei0; eidx[t * 2 + 1] = ei1;
            fw[t * 2] = f0; fw[t * 2 + 1] = f1;
            dmsum[t] = f0 + f1;
            #pragma unroll
            for (int e = 0; e < 8; ++e)
                load8[e] += ((e == ei0) ? f0 : 0.f) + ((e == ei1) ? f1 : 0.f);
            sqg += gl0 * gl0 + gl1 * gl1;
            sqe += el[0] * el[0] + el[1] * el[1] + el[2] * el[2] + el[3] * el[3];
        }
    }
    if (lane == 0) {
        #pragma unroll
        for (int e = 0; e < 8; ++e) sh[wv][e] = load8[e];
        sh[wv][8] = sqg; sh[wv][9] = sqe;
    }
    __syncthreads();
    if (tid < 10) {
        rpart[rb * 10 + tid] =
            sh[0][tid] + sh[1][tid] + sh[2][tid] + sh[3][tid];
    }
}

// ---------------- fused LayerNorm + transpose (pre -> adapt_in, adapt_inT) ----
__global__ __launch_bounds__(256) void lntr_k(const float* __restrict__ in,
                                              unsigned short* __restrict__ outn,
                                              unsigned short* __restrict__ outt,
                                              const float* __restrict__ gg,
                                              const float* __restrict__ bb)
{
    __shared__ unsigned short L[64][130];
    const int z = blockIdx.y;
    const int t0 = blockIdx.x * 64;
    const int wv = threadIdx.x >> 6, lane = threadIdx.x & 63;
    const float g0 = gg[lane], g1 = gg[lane + 64];
    const float b0 = bb[lane], b1 = bb[lane + 64];

    #pragma unroll 4
    for (int it = 0; it < 16; ++it) {
        const int row = wv * 16 + it;
        const long long gr = (long long)(z * Sc + t0 + row) * 128;
        const float z0 = in[gr + lane], z1 = in[gr + 64 + lane];
        float s = z0 + z1;
        #pragma unroll
        for (int o = 32; o > 0; o >>= 1) s += __shfl_xor(s, o, 64);
        const float mu = s * (1.f / 128.f);
        const float d0 = z0 - mu, d1 = z1 - mu;
        float v = d0 * d0 + d1 * d1;
        #pragma unroll
        for (int o = 32; o > 0; o >>= 1) v += __shfl_xor(v, o, 64);
        const float r = rsqrtf(v * (1.f / 128.f) + LN_EPSc);
        L[row][lane] = f2b(d0 * r * g0 + b0);
        L[row][lane + 64] = f2b(d1 * r * g1 + b1);
    }
    __syncthreads();
    {
        const int row = threadIdx.x >> 2, seg = (threadIdx.x & 3) * 32;
        #pragma unroll
        for (int j = 0; j < 8; ++j)
            *(us4*)&outn[(long long)(z * Sc + t0 + row) * 128 + seg + j * 4] =
                *(const us4*)&L[row][seg + j * 4];
    }
    {
        const int a = threadIdx.x >> 1, tt0 = (threadIdx.x & 1) * 32;
        #pragma unroll
        for (int j4 = 0; j4 < 8; ++j4) {
            us4 o;
            o.x = L[tt0 + j4 * 4 + 0][a]; o.y = L[tt0 + j4 * 4 + 1][a];
            o.z = L[tt0 + j4 * 4 + 2][a]; o.w = L[tt0 + j4 * 4 + 3][a];
            *(us4*)&outt[(long long)z * Ac * Sc + (long long)a * Sc + t0 + tt0 + j4 * 4] = o;
        }
    }
}

// ---------------- fused 4-way reduce + LayerNorm (post path) ----------------
__global__ __launch_bounds__(64) void redln_k(const float* __restrict__ in,
                                              unsigned short* __restrict__ out,
                                              const float* __restrict__ gg,
                                              const float* __restrict__ bb,
                                              long long pstride)
{
    const int row = blockIdx.x;
    const int lane = threadIdx.x;
    float z0 = 0.f, z1 = 0.f;
    #pragma unroll
    for (int p = 0; p < 4; ++p) {
        z0 += in[p * pstride + (long long)row * 128 + lane];
        z1 += in[p * pstride + (long long)row * 128 + 64 + lane];
    }
    float s = z0 + z1;
    for (int o = 32; o > 0; o >>= 1) s += __shfl_xor(s, o, 64);
    const float mu = s * (1.f / 128.f);
    const float d0 = z0 - mu, d1 = z1 - mu;
    float v = d0 * d0 + d1 * d1;
    for (int o = 32; o > 0; o >>= 1) v += __shfl_xor(v, o, 64);
    const float r = rsqrtf(v * (1.f / 128.f) + LN_EPSc);
    out[(long long)row * 128 + lane] = f2b(d0 * r * gg[lane] + bb[lane]);
    out[(long long)row * 128 + 64 + lane] = f2b(d1 * r * gg[lane + 64] + bb[lane + 64]);
}

// ---------------- loss reduce over RBLK partial rows ----------------
__global__ __launch_bounds__(512) void loss_k(const float* __restrict__ rpart,
                                              float* __restrict__ out_loss)
{
    const int tid = threadIdx.x;
    const int lane = tid & 63, wv = tid >> 6;
    float v[10];
    #pragma unroll
    for (int c = 0; c < 10; ++c) v[c] = rpart[tid * 10 + c];
    #pragma unroll
    for (int o = 32; o > 0; o >>= 1)
        #pragma unroll
        for (int c = 0; c < 10; ++c) v[c] += __shfl_xor(v[c], o, 64);
    __shared__ float sh[8][10];
    if (lane == 0) {
        #pragma unroll
        for (int c = 0; c < 10; ++c) sh[wv][c] = v[c];
    }
    __syncthreads();
    if (tid == 0) {
        float load[8]; float sqg = 0.f, sqe = 0.f;
        #pragma unroll
        for (int e = 0; e < 8; ++e) load[e] = 0.f;
        for (int wvi = 0; wvi < 8; ++wvi) {
            #pragma unroll
            for (int e = 0; e < 8; ++e) load[e] += sh[wvi][e];
            sqg += sh[wvi][8]; sqe += sh[wvi][9];
        }
        float s = 0.f;
        for (int e = 0; e < Ec; ++e) s += load[e];
        const float tgt = s / (float)Ec;
        float var = 0.f;
        for (int e = 0; e < Ec; ++e) { const float d = load[e] - tgt; var += d * d; }
        var /= (float)Ec;
        const float l = var + sqg / (float)(Nc * Gc) + sqe / (float)(Nc * GSc);
        *out_loss = 0.001f * l;
    }
}

// ---------------- combine: h2[t] = sum_slot fw * LN_e(h_dense[e][t]) ----------------
__global__ __launch_bounds__(128) void combine_k(const float* __restrict__ h_dense,
                                                 const float* __restrict__ ln_g_e,
                                                 const float* __restrict__ ln_b_e,
                                                 const int* __restrict__ eidx,
                                                 const float* __restrict__ fw,
                                                 unsigned short* __restrict__ h2)
{
    const int t = blockIdx.x;
    const int tid = threadIdx.x;
    __shared__ float red[2];

    float acc = 0.f;
    #pragma unroll
    for (int slot = 0; slot < 2; ++slot) {
        const int e = eidx[t * 2 + slot];
        const float w = fw[t * 2 + slot];
        const float h = h_dense[((long long)e * Nc + t) * 128 + tid];
        float v = h;
        for (int o = 32; o > 0; o >>= 1) v += __shfl_down(v, o, 64);
        if ((tid & 63) == 0) red[tid >> 6] = v;
        __syncthreads();
        const float mu = (red[0] + red[1]) * (1.f / 128.f);
        __syncthreads();
        const float d = h - mu;
        v = d * d;
        for (int o = 32; o > 0; o >>= 1) v += __shfl_down(v, o, 64);
        if ((tid & 63) == 0) red[tid >> 6] = v;
        __syncthreads();
        const float var = (red[0] + red[1]) * (1.f / 128.f);
        __syncthreads();
        acc += w * (d * rsqrtf(var + LN_EPSc) * ln_g_e[e * 128 + tid] + ln_b_e[e * 128 + tid]);
    }
    h2[(long long)t * 128 + tid] = f2b(acc);
}

// =====================================================================
extern "C" void kernel_launch(void* const* d_in, const int* in_sizes, int n_in,
                              void* d_out, int out_size, void* d_ws, size_t ws_size,
                              hipStream_t stream)
{
    const float* x       = (const float*)d_in[0];
    const float* W_up    = (const float*)d_in[1];
    const float* W_gate  = (const float*)d_in[2];
    const float* W_down  = (const float*)d_in[3];
    const float* W_pre   = (const float*)d_in[4];
    const float* W_post  = (const float*)d_in[5];
    const float* ln_g    = (const float*)d_in[6];
    const float* ln_b    = (const float*)d_in[7];
    const float* W_aproj = (const float*)d_in[8];
    const float* A_exp   = (const float*)d_in[9];
    const float* ln_g_e  = (const float*)d_in[10];
    const float* ln_b_e  = (const float*)d_in[11];
    const float* W_eproj = (const float*)d_in[12];
    const float* W_oproj = (const float*)d_in[13];
    const float* W_rg    = (const float*)d_in[14];
    const float* W_re    = (const float*)d_in[15];

    float* out = (float*)d_out;

    // ---- workspace carve ----
    char* p = (char*)d_ws;
    auto alloc = [&](size_t bytes) { void* r = (void*)p; p += (bytes + 255) & ~(size_t)255; return r; };
    float* pre      = (float*)alloc((size_t)Nc * Ac * 4);
    float* h_dense  = (float*)alloc((size_t)Ec * Nc * Ac * 4);   // scratch: wprepP / postP / h_dense / adaptP
    float* rpart    = (float*)alloc((size_t)RBLK * 10 * 4);
    float* fw       = (float*)alloc((size_t)Nc * 2 * 4);
    float* dmsum    = (float*)alloc((size_t)Nc * 4);
    int*   eidx     = (int*)alloc((size_t)Nc * 2 * 4);
    unsigned short* xb      = (unsigned short*)alloc((size_t)Nc * Dc * 2);
    unsigned short* Wcat_b  = (unsigned short*)alloc((size_t)(2 * Hc + Ac) * Dc * 2);
    unsigned short* Wd_b    = (unsigned short*)alloc((size_t)Dc * Hc * 2);
    unsigned short* Wop_b   = (unsigned short*)alloc((size_t)Dc * Hc * 2);
    unsigned short* Wpost_b = (unsigned short*)alloc((size_t)Ac * Hc * 2);
    unsigned short* WapT_b  = (unsigned short*)alloc((size_t)Ac * Hc * 2);
    unsigned short* WepT_b  = (unsigned short*)alloc((size_t)Ac * Hc * 2);
    unsigned short* Wdap_b  = (unsigned short*)alloc((size_t)Dc * Ac * 2);
    unsigned short* Wopep_b = (unsigned short*)alloc((size_t)Dc * Ac * 2);
    unsigned short* Aexp_b  = (unsigned short*)alloc((size_t)Ec * Ac * Ac * 2);
    unsigned short* pre_b   = (unsigned short*)alloc((size_t)Nc * Ac * 2);
    unsigned short* hidden  = (unsigned short*)alloc((size_t)Nc * Hc * 2);
    unsigned short* adapt_in  = (unsigned short*)alloc((size_t)Nc * Ac * 2);
    unsigned short* adapt_inT = (unsigned short*)alloc((size_t)Nc * Ac * 2);
    unsigned short* adapt_out = (unsigned short*)alloc((size_t)Nc * Ac * 2);
    unsigned short* adaptb    = (unsigned short*)alloc((size_t)Nc * Ac * 2);
    unsigned short* h2        = (unsigned short*)alloc((size_t)Nc * Ac * 2);

    float* wprepP = h_dense;   // [4 split][2 pair][1024*128] f32
    float* postP  = h_dense;   // [4][4096*128] f32
    float* adaptP = h_dense;   // [8][2][2048*128] f32

    // ---- merged weight prep + router ----
    PrepArgs pa;
    pa.csrc[0] = W_down;  pa.cdst[0] = Wd_b;    pa.cn4[0] = Dc * Hc / 4;
    pa.csrc[1] = W_oproj; pa.cdst[1] = Wop_b;   pa.cn4[1] = Dc * Hc / 4;
    pa.csrc[2] = W_post;  pa.cdst[2] = Wpost_b; pa.cn4[2] = Ac * Hc / 4;
    pa.csrc[3] = A_exp;   pa.cdst[3] = Aexp_b;  pa.cn4[3] = Ec * Ac * Ac / 4;
    pa.Wg = W_gate; pa.Wu = W_up; pa.Wpre = W_pre; pa.Wcat = Wcat_b;
    pa.tin0 = W_aproj; pa.tin1 = W_eproj; pa.tout0 = WapT_b; pa.tout1 = WepT_b;
    preprt_k<<<384 + RBLK, 256, 0, stream>>>(pa, x, W_rg, W_re, eidx, fw, dmsum, rpart, xb);
    loss_k<<<1, 512, 0, stream>>>(rpart, out + (size_t)Nc * Dc);

    // ---- Wdap/Wopep split-K (4x512), z=(pair,split), then alpha=0.1 reduce ----
    mgemm64<<<dim3(2, 8, 8), 256, 0, stream>>>(Wd_b, WapT_b, wprepP, Ac, 512, Hc, Hc,
        2,
        (long long)Dc * Hc, (long long)Ac * Hc, (long long)Dc * Ac,
        512, 512, (long long)2 * Dc * Ac);
    reduce_k<4, 1><<<256, 256, 0, stream>>>(wprepP, Wdap_b,
        (long long)2 * Dc * Ac, 2 * Dc * Ac / 4, 0.1f);

    // ---- fused gate+up+pre (BK=64, PR=8 x PC=3 panel swizzle) ----
    mgemm<9><<<dim3(33, 32), 256, 0, stream>>>(xb, Wcat_b, hidden, 2 * Hc + Ac, Dc, Dc, Dc,
        8, 3, 0.f, pre, pre_b, 0, 0, 0);
    lntr_k<<<dim3(Sc / 64, Bc), 256, 0, stream>>>(pre, adapt_in, adapt_inT, ln_g, ln_b);

    // ---- post split-K via mgemm (single 128-wide x-tile, z=4 K-splits) ----
    mgemm<0><<<dim3(1, 32, 4), 256, 0, stream>>>(hidden, Wpost_b, postP, Ac, 512, Hc, Hc,
        4, 1, 0.f, nullptr, nullptr, 512, 512, (long long)Nc * Ac);
    redln_k<<<Nc, 64, 0, stream>>>(postP, adapt_out, ln_g, ln_b, (long long)Nc * Ac);

    // ---- dense expert adapter via mgemm: h_dense[e] = pre_b @ A_exp[e]^T ----
    mgemm<0><<<dim3(1, 32, Ec), 256, 0, stream>>>(pre_b, Aexp_b, h_dense, Ac, Ac, Ac, Ac,
        4, 1, 0.f, nullptr, nullptr, 0, (long long)Ac * Ac, (long long)Nc * Ac);
    combine_k<<<Nc, 128, 0, stream>>>(h_dense, ln_g_e, ln_b_e, eidx, fw, h2);

    // ---- fused aw+adapt (direct-global fragments, QBLK=64, 512 blocks) ----
    fadapt_k<<<dim3(8, 32, 2), 256, 0, stream>>>(adapt_in, adapt_out, adapt_inT, adaptP);
    reduce_k<8, 1><<<512, 256, 0, stream>>>(adaptP, adaptb,
        (long long)2 * Sc * Ac, 2 * Sc * Ac / 4, 1.f);

    // ---- final fused (BK=64, PR=4 x PC=4 panel swizzle) ----
    final_k<<<dim3(Dc / 64, Nc / 128), 256, 0, stream>>>(
        hidden, Wd_b, adaptb, Wdap_b, h2, Wopep_b, dmsum, out);
}

// Round 19
// 183.841 us; speedup vs baseline: 1.0914x; 1.0321x over previous
//
#include <hip/hip_runtime.h>
#include <hip/hip_bf16.h>
#include <math.h>

static constexpr int Bc = 2;
static constexpr int Sc = 2048;
static constexpr int Dc = 1024;
static constexpr int Hc = 2048;
static constexpr int Ac = 128;
static constexpr int Ec = 8;
static constexpr int GSc = 4;
static constexpr int Gc = 2;
static constexpr int Nc = Bc * Sc;   // 4096 tokens
static constexpr float LN_EPSc = 1e-5f;
static constexpr int RBLK = 512;     // router blocks
static constexpr int NPREP = 434;    // byte-proportional prep blocks

typedef __attribute__((ext_vector_type(8))) short bf16x8;
typedef __attribute__((ext_vector_type(4))) float f32x4;
typedef __attribute__((ext_vector_type(4))) unsigned short us4;

__device__ __forceinline__ unsigned short f2b(float f) {
    union { float f; unsigned u; } v; v.f = f;
    return (unsigned short)((v.u + 0x7FFFu + ((v.u >> 16) & 1u)) >> 16);
}
__device__ __forceinline__ float b2f(unsigned short h) {
    union { unsigned u; float f; } v; v.u = (unsigned)h << 16; return v.f;
}
__device__ __forceinline__ float fsilu(float x) {
    return x / (1.f + __expf(-x));
}

#define GLOAD16(g, l) __builtin_amdgcn_global_load_lds( \
    (const __attribute__((address_space(1))) void*)(g), \
    (__attribute__((address_space(3))) void*)(l), 16, 0, 0)

// 2-D L2-panel swizzle: XCD k executes a contiguous chunk of tile-order; order
// tiles in PR-row x PC-col panels so each chunk's working set fits per-XCD L2.
__device__ __forceinline__ void panel_swizzle(int gx, int gy, int PR, int PC,
                                              int& bx, int& by)
{
    const int nwg = gx * gy;
    const int flat = blockIdx.y * gx + blockIdx.x;
    const int ord = (flat & 7) * (nwg >> 3) + (flat >> 3);   // XCD chunking
    const int srw = gx * PR;            // tiles per super-row
    const int sr = ord / srw;
    int rem = ord % srw;
    const int pi = rem / (PR * PC);
    rem %= (PR * PC);
    by = sr * PR + rem / PC;
    bx = pi * PC + rem % PC;
}

// ---------------- bf16 MFMA GEMM, 128x128 tile, BK=64, bank-swizzled ----------
// (round-9 proven structure). EPI 9 = gateup paired silu + pre side-channel.
// EPI 0 = f32 store (also used split-K via blockIdx.z strides).
template<int EPI>
__global__ __launch_bounds__(256, 4) void mgemm(
    const unsigned short* __restrict__ Ag, const unsigned short* __restrict__ Bg,
    void* __restrict__ Cg, int N, int K, int lda, int ldb, int PR, int PC, float alpha,
    float* __restrict__ aux, void* __restrict__ aux2,
    long long sA, long long sB, long long sC)
{
    __shared__ unsigned short As[128 * 64];
    __shared__ unsigned short Bs[128 * 64];
    const unsigned short* A = Ag + (long long)blockIdx.z * sA;
    const unsigned short* B = Bg + (long long)blockIdx.z * sB;
    float* fC = (float*)Cg + (long long)blockIdx.z * sC;
    unsigned short* usC = (unsigned short*)Cg + (long long)blockIdx.z * sC;

    int bx, by;
    panel_swizzle(gridDim.x, gridDim.y, PR, PC, bx, by);
    const int bm = by * 128, bn = bx * 128;

    const int tid = threadIdx.x;
    const int w = tid >> 6, l = tid & 63;
    const int wm = (w >> 1) * 64, wn = (w & 1) * 64;
    const int fr = l & 15, g = l >> 4;

    const f32x4 zero = { 0.f, 0.f, 0.f, 0.f };
    f32x4 acc[4][4];
    #pragma unroll
    for (int i = 0; i < 4; ++i)
        #pragma unroll
        for (int j = 0; j < 4; ++j) acc[i][j] = zero;

    for (int k0 = 0; k0 < K; k0 += 64) {
        #pragma unroll
        for (int p = 0; p < 4; ++p) {
            const int c = p * 256 + tid;
            const int row = c >> 3;
            const int gch = (c & 7) ^ ((c >> 4) & 7);
            GLOAD16(A + (long long)(bm + row) * lda + k0 + gch * 8, &As[c * 8]);
            GLOAD16(B + (long long)(bn + row) * ldb + k0 + gch * 8, &Bs[c * 8]);
        }
        __syncthreads();
        #pragma unroll
        for (int h = 0; h < 2; ++h) {
            bf16x8 af[4], bfv[4];
            #pragma unroll
            for (int i = 0; i < 4; ++i) {
                const int ra = wm + i * 16 + fr;
                af[i]  = *(const bf16x8*)&As[ra * 64 + ((h * 4 + g) ^ ((ra >> 1) & 7)) * 8];
                const int rb = wn + i * 16 + fr;
                bfv[i] = *(const bf16x8*)&Bs[rb * 64 + ((h * 4 + g) ^ ((rb >> 1) & 7)) * 8];
            }
            #pragma unroll
            for (int i = 0; i < 4; ++i)
                #pragma unroll
                for (int j = 0; j < 4; ++j)
                    acc[i][j] = __builtin_amdgcn_mfma_f32_16x16x32_bf16(af[i], bfv[j], acc[i][j], 0, 0, 0);
        }
        __syncthreads();
    }

    if (EPI == 9) {
        if (bn < 2 * Hc) {
            #pragma unroll
            for (int mi = 0; mi < 4; ++mi) {
                #pragma unroll
                for (int j = 0; j < 2; ++j) {
                    #pragma unroll
                    for (int jr = 0; jr < 4; ++jr) {
                        const long long row = bm + wm + mi * 16 + g * 4 + jr;
                        const long long colh = ((bn + wn) >> 1) + j * 16 + fr;
                        const float gv = acc[mi][2 * j][jr];
                        const float uv = acc[mi][2 * j + 1][jr];
                        usC[row * Hc + colh] = f2b(fsilu(gv) * uv);
                    }
                }
            }
        } else {
            unsigned short* preb = (unsigned short*)aux2;
            #pragma unroll
            for (int mi = 0; mi < 4; ++mi) {
                #pragma unroll
                for (int ni = 0; ni < 4; ++ni) {
                    #pragma unroll
                    for (int jr = 0; jr < 4; ++jr) {
                        const long long row = bm + wm + mi * 16 + g * 4 + jr;
                        const int lc = wn + ni * 16 + fr;
                        const float v = acc[mi][ni][jr];
                        aux[row * Ac + lc] = v;
                        preb[row * Ac + lc] = f2b(v);
                    }
                }
            }
        }
    } else {
        #pragma unroll
        for (int mi = 0; mi < 4; ++mi)
            #pragma unroll
            for (int ni = 0; ni < 4; ++ni)
                #pragma unroll
                for (int jr = 0; jr < 4; ++jr) {
                    const long long row = bm + wm + mi * 16 + g * 4 + jr;
                    const long long col = bn + wn + ni * 16 + fr;
                    const long long idx = row * (long long)N + col;
                    const float v = acc[mi][ni][jr];
                    if (EPI == 0) fC[idx] = v;
                    else usC[idx] = f2b(alpha * v);
                }
    }
}

// ---------------- bf16 MFMA GEMM, 128x64 tile (f32 out), BK=32, 2-axis z -----
// (used only for the Wdap/Wopep split-K prep now)
__global__ __launch_bounds__(256, 2) void mgemm64(
    const unsigned short* __restrict__ Ag, const unsigned short* __restrict__ Bg,
    float* __restrict__ Cg, int N, int K, int lda, int ldb, int zmod,
    long long sA1, long long sB1, long long sC1,
    long long sA2, long long sB2, long long sC2)
{
    __shared__ unsigned short As[128 * 32];
    __shared__ unsigned short Bs[64 * 32];
    const int z1 = blockIdx.z % zmod, z2 = blockIdx.z / zmod;
    const unsigned short* A = Ag + (long long)z1 * sA1 + (long long)z2 * sA2;
    const unsigned short* B = Bg + (long long)z1 * sB1 + (long long)z2 * sB2;
    float* fC = Cg + (long long)z1 * sC1 + (long long)z2 * sC2;

    const int nwg = gridDim.x * gridDim.y;
    const int flat = blockIdx.y * gridDim.x + blockIdx.x;
    const int swz = (flat & 7) * (nwg >> 3) + (flat >> 3);
    const int bx = swz % gridDim.x, by = swz / gridDim.x;
    const int bm = by * 128, bn = bx * 64;

    const int tid = threadIdx.x;
    const int w = tid >> 6, l = tid & 63;
    const int wm = (w >> 1) * 64, wn = (w & 1) * 32;
    const int fr = l & 15, g = l >> 4;

    const f32x4 zero = { 0.f, 0.f, 0.f, 0.f };
    f32x4 acc[4][2];
    #pragma unroll
    for (int i = 0; i < 4; ++i)
        #pragma unroll
        for (int j = 0; j < 2; ++j) acc[i][j] = zero;

    for (int k0 = 0; k0 < K; k0 += 32) {
        #pragma unroll
        for (int p = 0; p < 2; ++p) {
            const int c = p * 256 + tid;
            GLOAD16(A + (long long)(bm + (c >> 2)) * lda + k0 + (c & 3) * 8, &As[c * 8]);
        }
        GLOAD16(B + (long long)(bn + (tid >> 2)) * ldb + k0 + (tid & 3) * 8, &Bs[tid * 8]);
        __syncthreads();
        bf16x8 af[4], bfv[2];
        #pragma unroll
        for (int i = 0; i < 4; ++i)
            af[i]  = *(const bf16x8*)&As[(wm + i * 16 + fr) * 32 + g * 8];
        #pragma unroll
        for (int j = 0; j < 2; ++j)
            bfv[j] = *(const bf16x8*)&Bs[(wn + j * 16 + fr) * 32 + g * 8];
        #pragma unroll
        for (int i = 0; i < 4; ++i)
            #pragma unroll
            for (int j = 0; j < 2; ++j)
                acc[i][j] = __builtin_amdgcn_mfma_f32_16x16x32_bf16(af[i], bfv[j], acc[i][j], 0, 0, 0);
        __syncthreads();
    }

    #pragma unroll
    for (int mi = 0; mi < 4; ++mi)
        #pragma unroll
        for (int ni = 0; ni < 2; ++ni)
            #pragma unroll
            for (int jr = 0; jr < 4; ++jr) {
                const long long row = bm + wm + mi * 16 + g * 4 + jr;
                const long long col = bn + wn + ni * 16 + fr;
                fC[row * (long long)N + col] = acc[mi][ni][jr];
            }
}

// ---------------- fused aw+adapt: direct-global fragments, QBLK=64 ------------
// (round-13 exact)
__global__ __launch_bounds__(256, 2) void fadapt_k(
    const unsigned short* __restrict__ adapt_in,
    const unsigned short* __restrict__ adapt_out,
    const unsigned short* __restrict__ adapt_inT,
    float* __restrict__ partial)
{
    __shared__ unsigned short P_lds[4 * 64 * 32];   // [ks][qrow][chunk-swizzled]

    const int b = blockIdx.z;
    const int q0 = blockIdx.y * 64;
    const int t0 = blockIdx.x * 256;

    const unsigned short* Qg = adapt_in + (long long)b * Sc * Ac;
    const unsigned short* Kg = adapt_out + (long long)b * Sc * Ac;
    const unsigned short* Vt = adapt_inT + (long long)b * Ac * Sc;

    const int tid = threadIdx.x;
    const int w = tid >> 6, l = tid & 63;
    const int wm = (w >> 1) * 32, wn = (w & 1) * 64;
    const int fr = l & 15, g = l >> 4;

    bf16x8 qf[2][4];
    #pragma unroll
    for (int i = 0; i < 2; ++i) {
        const long long ra = q0 + wm + i * 16 + fr;
        #pragma unroll
        for (int ks = 0; ks < 4; ++ks)
            qf[i][ks] = *(const bf16x8*)&Qg[ra * Ac + ks * 32 + g * 8];
    }

    const f32x4 zero = { 0.f, 0.f, 0.f, 0.f };
    f32x4 acc[2][4];
    #pragma unroll
    for (int i = 0; i < 2; ++i)
        #pragma unroll
        for (int j = 0; j < 4; ++j) acc[i][j] = zero;

    #pragma unroll 1
    for (int ts = 0; ts < 2; ++ts) {
        const int t1 = t0 + ts * 128;
        f32x4 sacc[2][4];
        #pragma unroll
        for (int i = 0; i < 2; ++i)
            #pragma unroll
            for (int j = 0; j < 4; ++j) sacc[i][j] = zero;
        #pragma unroll
        for (int ks = 0; ks < 4; ++ks) {
            bf16x8 bfv[4];
            #pragma unroll
            for (int j = 0; j < 4; ++j) {
                const long long rb = t1 + wn + j * 16 + fr;
                bfv[j] = *(const bf16x8*)&Kg[rb * Ac + ks * 32 + g * 8];
            }
            #pragma unroll
            for (int i = 0; i < 2; ++i)
                #pragma unroll
                for (int j = 0; j < 4; ++j)
                    sacc[i][j] = __builtin_amdgcn_mfma_f32_16x16x32_bf16(qf[i][ks], bfv[j], sacc[i][j], 0, 0, 0);
        }
        __syncthreads();
        #pragma unroll
        for (int mi = 0; mi < 2; ++mi) {
            #pragma unroll
            for (int ni = 0; ni < 4; ++ni) {
                const int t = wn + ni * 16 + fr;
                const int tl = t & 31;
                const int kbase = (t >> 5) * 2048;
                #pragma unroll
                for (int jr = 0; jr < 4; ++jr) {
                    const int row = wm + mi * 16 + g * 4 + jr;
                    float v = sacc[mi][ni][jr];
                    v = fminf(fmaxf(v, -5.f), 5.f);
                    const int pos = (((tl >> 3) ^ ((row >> 1) & 3)) << 3) + (tl & 7);
                    P_lds[kbase + row * 32 + pos] = f2b(fsilu(v));
                }
            }
        }
        __syncthreads();
        #pragma unroll
        for (int ks = 0; ks < 4; ++ks) {
            bf16x8 af[2], bfv[4];
            #pragma unroll
            for (int i = 0; i < 2; ++i) {
                const int ra = wm + i * 16 + fr;
                af[i] = *(const bf16x8*)&P_lds[ks * 2048 + ra * 32 + (g ^ ((ra >> 1) & 3)) * 8];
            }
            #pragma unroll
            for (int j = 0; j < 4; ++j) {
                const long long rb = wn + j * 16 + fr;
                bfv[j] = *(const bf16x8*)&Vt[rb * Sc + t1 + ks * 32 + g * 8];
            }
            #pragma unroll
            for (int i = 0; i < 2; ++i)
                #pragma unroll
                for (int j = 0; j < 4; ++j)
                    acc[i][j] = __builtin_amdgcn_mfma_f32_16x16x32_bf16(af[i], bfv[j], acc[i][j], 0, 0, 0);
        }
    }

    float* op = partial + ((long long)blockIdx.x * Bc + b) * Sc * Ac;
    #pragma unroll
    for (int mi = 0; mi < 2; ++mi)
        #pragma unroll
        for (int ni = 0; ni < 4; ++ni)
            #pragma unroll
            for (int jr = 0; jr < 4; ++jr) {
                const long long row = q0 + wm + mi * 16 + g * 4 + jr;
                const long long col = wn + ni * 16 + fr;
                op[row * Ac + col] = acc[mi][ni][jr];
            }
}

// ---------------- final fused 3-phase GEMM, 128x64 tile, BK=64, swizzled ------
__global__ __launch_bounds__(256, 2) void final_k(
    const unsigned short* __restrict__ hidden, const unsigned short* __restrict__ Wd,
    const unsigned short* __restrict__ adaptb, const unsigned short* __restrict__ Wdap,
    const unsigned short* __restrict__ h2v, const unsigned short* __restrict__ Wopep,
    const float* __restrict__ dmsum, float* __restrict__ out)
{
    __shared__ unsigned short As[128 * 64];
    __shared__ unsigned short Bs[64 * 64];

    int bx, by;
    panel_swizzle(gridDim.x, gridDim.y, 4, 4, bx, by);
    const int bm = by * 128, bn = bx * 64;

    const int tid = threadIdx.x;
    const int w = tid >> 6, l = tid & 63;
    const int wm = (w >> 1) * 64, wn = (w & 1) * 32;
    const int fr = l & 15, g = l >> 4;

    const f32x4 zero = { 0.f, 0.f, 0.f, 0.f };
    f32x4 acc[4][2];
    #pragma unroll
    for (int i = 0; i < 4; ++i)
        #pragma unroll
        for (int j = 0; j < 2; ++j) acc[i][j] = zero;

    const unsigned short* Ap[3] = { hidden, adaptb, h2v };
    const unsigned short* Bp[3] = { Wd, Wdap, Wopep };
    const int Ks[3] = { Hc, Ac, Ac };

    #pragma unroll 1
    for (int ph = 0; ph < 3; ++ph) {
        if (ph == 2) {
            #pragma unroll
            for (int mi = 0; mi < 4; ++mi)
                #pragma unroll
                for (int jr = 0; jr < 4; ++jr) {
                    const float rs = dmsum[bm + wm + mi * 16 + g * 4 + jr];
                    #pragma unroll
                    for (int ni = 0; ni < 2; ++ni) acc[mi][ni][jr] *= rs;
                }
        }
        const unsigned short* A = Ap[ph];
        const unsigned short* B = Bp[ph];
        const int K = Ks[ph];
        for (int k0 = 0; k0 < K; k0 += 64) {
            #pragma unroll
            for (int p = 0; p < 4; ++p) {
                const int c = p * 256 + tid;
                const int row = c >> 3;
                const int gch = (c & 7) ^ ((c >> 4) & 7);
                GLOAD16(A + (long long)(bm + row) * K + k0 + gch * 8, &As[c * 8]);
            }
            #pragma unroll
            for (int p = 0; p < 2; ++p) {
                const int c = p * 256 + tid;
                const int row = c >> 3;
                const int gch = (c & 7) ^ ((c >> 4) & 7);
                GLOAD16(B + (long long)(bn + row) * K + k0 + gch * 8, &Bs[c * 8]);
            }
            __syncthreads();
            #pragma unroll
            for (int h = 0; h < 2; ++h) {
                bf16x8 af[4], bfv[2];
                #pragma unroll
                for (int i = 0; i < 4; ++i) {
                    const int ra = wm + i * 16 + fr;
                    af[i]  = *(const bf16x8*)&As[ra * 64 + ((h * 4 + g) ^ ((ra >> 1) & 7)) * 8];
                }
                #pragma unroll
                for (int j = 0; j < 2; ++j) {
                    const int rb = wn + j * 16 + fr;
                    bfv[j] = *(const bf16x8*)&Bs[rb * 64 + ((h * 4 + g) ^ ((rb >> 1) & 7)) * 8];
                }
                #pragma unroll
                for (int i = 0; i < 4; ++i)
                    #pragma unroll
                    for (int j = 0; j < 2; ++j)
                        acc[i][j] = __builtin_amdgcn_mfma_f32_16x16x32_bf16(af[i], bfv[j], acc[i][j], 0, 0, 0);
            }
            __syncthreads();
        }
    }

    #pragma unroll
    for (int mi = 0; mi < 4; ++mi)
        #pragma unroll
        for (int ni = 0; ni < 2; ++ni)
            #pragma unroll
            for (int jr = 0; jr < 4; ++jr) {
                const long long row = bm + wm + mi * 16 + g * 4 + jr;
                const long long col = bn + wn + ni * 16 + fr;
                out[row * (long long)Dc + col] = acc[mi][ni][jr];
            }
}

// ---------------- partial-sum reduce: out = alpha * sum_p in[p*stride + i] ----
template<int NP, int BF>
__global__ __launch_bounds__(256) void reduce_k(const float* __restrict__ in,
                                                void* __restrict__ outp,
                                                long long pstride, int n4, float alpha)
{
    for (int i = blockIdx.x * 256 + threadIdx.x; i < n4; i += gridDim.x * 256) {
        float4 s = ((const float4*)in)[i];
        #pragma unroll
        for (int p = 1; p < NP; ++p) {
            const float4 v = ((const float4*)(in + (long long)p * pstride))[i];
            s.x += v.x; s.y += v.y; s.z += v.z; s.w += v.w;
        }
        s.x *= alpha; s.y *= alpha; s.z *= alpha; s.w *= alpha;
        if (BF) {
            us4 o = { f2b(s.x), f2b(s.y), f2b(s.z), f2b(s.w) };
            ((us4*)outp)[i] = o;
        } else {
            ((float4*)outp)[i] = s;
        }
    }
}

// ---------------- merged prep + router kernel (byte-proportional prep) --------
// blocks [0,NPREP): weight prep, segments sized by bytes moved:
//   seg0 W_down 96 | seg1 W_oproj 96 | seg2 W_post 12 | seg3 A_exp 6
//   seg4 Wcat 192 | seg5 transpose 32
// blocks [NPREP, NPREP+RBLK): router (also emits xb)
struct PrepArgs {
    const float* csrc[4]; unsigned short* cdst[4]; int cn4[4];
    const float* Wg; const float* Wu; const float* Wpre; unsigned short* Wcat;
    const float* tin0; const float* tin1; unsigned short* tout0; unsigned short* tout1;
};
__global__ __launch_bounds__(256) void preprt_k(PrepArgs a,
    const float* __restrict__ x, const float* __restrict__ W_rg,
    const float* __restrict__ W_re, int* __restrict__ eidx,
    float* __restrict__ fw, float* __restrict__ dmsum,
    float* __restrict__ rpart, unsigned short* __restrict__ xb)
{
    __shared__ float T[64][68];
    __shared__ float sh[4][10];
    const int tid = threadIdx.x;

    if (blockIdx.x < NPREP) {
        int seg, base, nblk;
        const int b = blockIdx.x;
        if (b < 96)       { seg = 0; base = 0;   nblk = 96; }
        else if (b < 192) { seg = 1; base = 96;  nblk = 96; }
        else if (b < 204) { seg = 2; base = 192; nblk = 12; }
        else if (b < 210) { seg = 3; base = 204; nblk = 6;  }
        else if (b < 402) { seg = 4; base = 210; nblk = 192; }
        else              { seg = 5; base = 402; nblk = 32; }
        const int bx = b - base;

        if (seg < 4) {
            const float4* s = (const float4*)a.csrc[seg];
            us4* d = (us4*)a.cdst[seg];
            const int n = a.cn4[seg];
            for (int i = bx * 256 + tid; i < n; i += nblk * 256) {
                const float4 v = s[i];
                us4 o;
                o.x = f2b(v.x); o.y = f2b(v.y); o.z = f2b(v.z); o.w = f2b(v.w);
                d[i] = o;
            }
        } else if (seg == 4) {
            const int total = (2 * Hc + Ac) * 256;
            for (int u = bx * 256 + tid; u < total; u += nblk * 256) {
                const int r = u >> 8, t = u & 255;
                const float* src; int srcrow;
                if (r < 2 * Hc) {
                    const int bb = r >> 5, wq = r & 31;
                    src = (wq < 16) ? a.Wg : a.Wu;
                    srcrow = bb * 16 + (wq & 15);
                } else {
                    src = a.Wpre;
                    srcrow = r - 2 * Hc;
                }
                const float4 v = ((const float4*)(src + (long long)srcrow * Dc))[t];
                us4 o;
                o.x = f2b(v.x); o.y = f2b(v.y); o.z = f2b(v.z); o.w = f2b(v.w);
                ((us4*)(a.Wcat + (long long)r * Dc))[t] = o;
            }
        } else {
            const int rr = tid >> 4, cc = (tid & 15) * 4;
            for (int tb = bx; tb < 128; tb += nblk) {
                const int z = tb >> 6, rem = tb & 63;
                const int a0 = (rem >> 5) * 64, t0 = (rem & 31) * 64;
                const float* in = z ? a.tin1 : a.tin0;
                unsigned short* outp = z ? a.tout1 : a.tout0;
                __syncthreads();
                #pragma unroll
                for (int p = 0; p < 4; ++p) {
                    const int row = p * 16 + rr;
                    *(float4*)&T[row][cc] = *(const float4*)&in[(long long)(t0 + row) * Ac + a0 + cc];
                }
                __syncthreads();
                #pragma unroll
                for (int p = 0; p < 4; ++p) {
                    const int ar = p * 16 + rr;
                    us4 o;
                    o.x = f2b(T[cc + 0][ar]); o.y = f2b(T[cc + 1][ar]);
                    o.z = f2b(T[cc + 2][ar]); o.w = f2b(T[cc + 3][ar]);
                    *(us4*)&outp[(long long)(a0 + ar) * Hc + t0 + cc] = o;
                }
            }
        }
        return;
    }

    // ---- router path ----
    const int rb = blockIdx.x - NPREP;
    const int wv = tid >> 6;
    const int lane = tid & 63;
    float load8[8] = {0.f, 0.f, 0.f, 0.f, 0.f, 0.f, 0.f, 0.f};
    float sqg = 0.f, sqe = 0.f;

    #pragma unroll
    for (int it = 0; it < 2; ++it) {
        const int t = rb * 8 + wv * 2 + it;
        const float* xr = x + (long long)t * Dc;
        float a0 = 0, a1 = 0, a2 = 0, a3 = 0, a4 = 0, a5 = 0;
        #pragma unroll
        for (int j = 0; j < 16; ++j) {
            const int d = lane + 64 * j;
            const float xv = xr[d];
            xb[(long long)t * Dc + d] = f2b(xv);
            a0 += xv * W_rg[d];          a1 += xv * W_rg[Dc + d];
            a2 += xv * W_re[d];          a3 += xv * W_re[Dc + d];
            a4 += xv * W_re[2 * Dc + d]; a5 += xv * W_re[3 * Dc + d];
        }
        #pragma unroll
        for (int o = 32; o > 0; o >>= 1) {
            a0 += __shfl_xor(a0, o, 64); a1 += __shfl_xor(a1, o, 64);
            a2 += __shfl_xor(a2, o, 64); a3 += __shfl_xor(a3, o, 64);
            a4 += __shfl_xor(a4, o, 64); a5 += __shfl_xor(a5, o, 64);
        }
        if (lane == 0) {
            const float gl0 = a0, gl1 = a1;
            const float m = fmaxf(gl0, gl1);
            const float e0 = expf(gl0 - m), e1 = expf(gl1 - m);
            const float inv = 1.f / (e0 + e1);
            const float gp0 = e0 * inv, gp1 = e1 * inv;
            const int gidx = (gl1 > gl0) ? 1 : 0;
            const float gw = fmaxf(gp0, gp1);
            float el[4] = { a2, a3, a4, a5 };
            const float me = fmaxf(fmaxf(el[0], el[1]), fmaxf(el[2], el[3]));
            float ep[4]; float se = 0.f;
            #pragma unroll
            for (int i = 0; i < 4; ++i) { ep[i] = expf(el[i] - me); se += ep[i]; }
            const float invs = 1.f / se;
            #pragma unroll
            for (int i = 0; i < 4; ++i) ep[i] *= invs;
            int i0 = 0;
            #pragma unroll
            for (int i = 1; i < 4; ++i) if (ep[i] > ep[i0]) i0 = i;
            int i1 = -1;
            #pragma unroll
            for (int i = 0; i < 4; ++i) { if (i == i0) continue; if (i1 < 0 || ep[i] > ep[i1]) i1 = i; }
            const float w0 = ep[i0], w1 = ep[i1];
            const float sn = w0 + w1 + 1e-7f;
            const float f0 = gw * w0 / sn, f1 = gw * w1 / sn;
            const int ei0 = gidx * GSc + i0, ei1 = gidx * GSc + i1;
            eidx[t * 2] = ei0; eidx[t * 2 + 1] = ei1;
            fw[t * 2] = f0; fw[t * 2 + 1] = f1;
            dmsum[t] = f0 + f1;
            #pragma unroll
            for (int e = 0; e < 8; ++e)
                load8[e] += ((e == ei0) ? f0 : 0.f) + ((e == ei1) ? f1 : 0.f);
            sqg += gl0 * gl0 + gl1 * gl1;
            sqe += el[0] * el[0] + el[1] * el[1] + el[2] * el[2] + el[3] * el[3];
        }
    }
    if (lane == 0) {
        #pragma unroll
        for (int e = 0; e < 8; ++e) sh[wv][e] = load8[e];
        sh[wv][8] = sqg; sh[wv][9] = sqe;
    }
    __syncthreads();
    if (tid < 10) {
        rpart[rb * 10 + tid] =
            sh[0][tid] + sh[1][tid] + sh[2][tid] + sh[3][tid];
    }
}

// ---------------- fused LayerNorm + transpose (pre -> adapt_in, adapt_inT) ----
__global__ __launch_bounds__(256) void lntr_k(const float* __restrict__ in,
                                              unsigned short* __restrict__ outn,
                                              unsigned short* __restrict__ outt,
                                              const float* __restrict__ gg,
                                              const float* __restrict__ bb)
{
    __shared__ unsigned short L[64][130];
    const int z = blockIdx.y;
    const int t0 = blockIdx.x * 64;
    const int wv = threadIdx.x >> 6, lane = threadIdx.x & 63;
    const float g0 = gg[lane], g1 = gg[lane + 64];
    const float b0 = bb[lane], b1 = bb[lane + 64];

    #pragma unroll 4
    for (int it = 0; it < 16; ++it) {
        const int row = wv * 16 + it;
        const long long gr = (long long)(z * Sc + t0 + row) * 128;
        const float z0 = in[gr + lane], z1 = in[gr + 64 + lane];
        float s = z0 + z1;
        #pragma unroll
        for (int o = 32; o > 0; o >>= 1) s += __shfl_xor(s, o, 64);
        const float mu = s * (1.f / 128.f);
        const float d0 = z0 - mu, d1 = z1 - mu;
        float v = d0 * d0 + d1 * d1;
        #pragma unroll
        for (int o = 32; o > 0; o >>= 1) v += __shfl_xor(v, o, 64);
        const float r = rsqrtf(v * (1.f / 128.f) + LN_EPSc);
        L[row][lane] = f2b(d0 * r * g0 + b0);
        L[row][lane + 64] = f2b(d1 * r * g1 + b1);
    }
    __syncthreads();
    {
        const int row = threadIdx.x >> 2, seg = (threadIdx.x & 3) * 32;
        #pragma unroll
        for (int j = 0; j < 8; ++j)
            *(us4*)&outn[(long long)(z * Sc + t0 + row) * 128 + seg + j * 4] =
                *(const us4*)&L[row][seg + j * 4];
    }
    {
        const int a = threadIdx.x >> 1, tt0 = (threadIdx.x & 1) * 32;
        #pragma unroll
        for (int j4 = 0; j4 < 8; ++j4) {
            us4 o;
            o.x = L[tt0 + j4 * 4 + 0][a]; o.y = L[tt0 + j4 * 4 + 1][a];
            o.z = L[tt0 + j4 * 4 + 2][a]; o.w = L[tt0 + j4 * 4 + 3][a];
            *(us4*)&outt[(long long)z * Ac * Sc + (long long)a * Sc + t0 + tt0 + j4 * 4] = o;
        }
    }
}

// ---------------- fused 4-way reduce + LayerNorm (post path) ----------------
__global__ __launch_bounds__(64) void redln_k(const float* __restrict__ in,
                                              unsigned short* __restrict__ out,
                                              const float* __restrict__ gg,
                                              const float* __restrict__ bb,
                                              long long pstride)
{
    const int row = blockIdx.x;
    const int lane = threadIdx.x;
    float z0 = 0.f, z1 = 0.f;
    #pragma unroll
    for (int p = 0; p < 4; ++p) {
        z0 += in[p * pstride + (long long)row * 128 + lane];
        z1 += in[p * pstride + (long long)row * 128 + 64 + lane];
    }
    float s = z0 + z1;
    for (int o = 32; o > 0; o >>= 1) s += __shfl_xor(s, o, 64);
    const float mu = s * (1.f / 128.f);
    const float d0 = z0 - mu, d1 = z1 - mu;
    float v = d0 * d0 + d1 * d1;
    for (int o = 32; o > 0; o >>= 1) v += __shfl_xor(v, o, 64);
    const float r = rsqrtf(v * (1.f / 128.f) + LN_EPSc);
    out[(long long)row * 128 + lane] = f2b(d0 * r * gg[lane] + bb[lane]);
    out[(long long)row * 128 + 64 + lane] = f2b(d1 * r * gg[lane + 64] + bb[lane + 64]);
}

// ---------------- loss reduce over RBLK partial rows ----------------
__global__ __launch_bounds__(512) void loss_k(const float* __restrict__ rpart,
                                              float* __restrict__ out_loss)
{
    const int tid = threadIdx.x;
    const int lane = tid & 63, wv = tid >> 6;
    float v[10];
    #pragma unroll
    for (int c = 0; c < 10; ++c) v[c] = rpart[tid * 10 + c];
    #pragma unroll
    for (int o = 32; o > 0; o >>= 1)
        #pragma unroll
        for (int c = 0; c < 10; ++c) v[c] += __shfl_xor(v[c], o, 64);
    __shared__ float sh[8][10];
    if (lane == 0) {
        #pragma unroll
        for (int c = 0; c < 10; ++c) sh[wv][c] = v[c];
    }
    __syncthreads();
    if (tid == 0) {
        float load[8]; float sqg = 0.f, sqe = 0.f;
        #pragma unroll
        for (int e = 0; e < 8; ++e) load[e] = 0.f;
        for (int wvi = 0; wvi < 8; ++wvi) {
            #pragma unroll
            for (int e = 0; e < 8; ++e) load[e] += sh[wvi][e];
            sqg += sh[wvi][8]; sqe += sh[wvi][9];
        }
        float s = 0.f;
        for (int e = 0; e < Ec; ++e) s += load[e];
        const float tgt = s / (float)Ec;
        float var = 0.f;
        for (int e = 0; e < Ec; ++e) { const float d = load[e] - tgt; var += d * d; }
        var /= (float)Ec;
        const float l = var + sqg / (float)(Nc * Gc) + sqe / (float)(Nc * GSc);
        *out_loss = 0.001f * l;
    }
}

// ---------------- combine: h2[t] = sum_slot fw * LN_e(h_dense[e][t]) ----------------
__global__ __launch_bounds__(128) void combine_k(const float* __restrict__ h_dense,
                                                 const float* __restrict__ ln_g_e,
                                                 const float* __restrict__ ln_b_e,
                                                 const int* __restrict__ eidx,
                                                 const float* __restrict__ fw,
                                                 unsigned short* __restrict__ h2)
{
    const int t = blockIdx.x;
    const int tid = threadIdx.x;
    __shared__ float red[2];

    float acc = 0.f;
    #pragma unroll
    for (int slot = 0; slot < 2; ++slot) {
        const int e = eidx[t * 2 + slot];
        const float w = fw[t * 2 + slot];
        const float h = h_dense[((long long)e * Nc + t) * 128 + tid];
        float v = h;
        for (int o = 32; o > 0; o >>= 1) v += __shfl_down(v, o, 64);
        if ((tid & 63) == 0) red[tid >> 6] = v;
        __syncthreads();
        const float mu = (red[0] + red[1]) * (1.f / 128.f);
        __syncthreads();
        const float d = h - mu;
        v = d * d;
        for (int o = 32; o > 0; o >>= 1) v += __shfl_down(v, o, 64);
        if ((tid & 63) == 0) red[tid >> 6] = v;
        __syncthreads();
        const float var = (red[0] + red[1]) * (1.f / 128.f);
        __syncthreads();
        acc += w * (d * rsqrtf(var + LN_EPSc) * ln_g_e[e * 128 + tid] + ln_b_e[e * 128 + tid]);
    }
    h2[(long long)t * 128 + tid] = f2b(acc);
}

// =====================================================================
extern "C" void kernel_launch(void* const* d_in, const int* in_sizes, int n_in,
                              void* d_out, int out_size, void* d_ws, size_t ws_size,
                              hipStream_t stream)
{
    const float* x       = (const float*)d_in[0];
    const float* W_up    = (const float*)d_in[1];
    const float* W_gate  = (const float*)d_in[2];
    const float* W_down  = (const float*)d_in[3];
    const float* W_pre   = (const float*)d_in[4];
    const float* W_post  = (const float*)d_in[5];
    const float* ln_g    = (const float*)d_in[6];
    const float* ln_b    = (const float*)d_in[7];
    const float* W_aproj = (const float*)d_in[8];
    const float* A_exp   = (const float*)d_in[9];
    const float* ln_g_e  = (const float*)d_in[10];
    const float* ln_b_e  = (const float*)d_in[11];
    const float* W_eproj = (const float*)d_in[12];
    const float* W_oproj = (const float*)d_in[13];
    const float* W_rg    = (const float*)d_in[14];
    const float* W_re    = (const float*)d_in[15];

    float* out = (float*)d_out;

    // ---- workspace carve ----
    char* p = (char*)d_ws;
    auto alloc = [&](size_t bytes) { void* r = (void*)p; p += (bytes + 255) & ~(size_t)255; return r; };
    float* pre      = (float*)alloc((size_t)Nc * Ac * 4);
    float* h_dense  = (float*)alloc((size_t)Ec * Nc * Ac * 4);   // scratch: wprepP / postP / h_dense / adaptP
    float* rpart    = (float*)alloc((size_t)RBLK * 10 * 4);
    float* fw       = (float*)alloc((size_t)Nc * 2 * 4);
    float* dmsum    = (float*)alloc((size_t)Nc * 4);
    int*   eidx     = (int*)alloc((size_t)Nc * 2 * 4);
    unsigned short* xb      = (unsigned short*)alloc((size_t)Nc * Dc * 2);
    unsigned short* Wcat_b  = (unsigned short*)alloc((size_t)(2 * Hc + Ac) * Dc * 2);
    unsigned short* Wd_b    = (unsigned short*)alloc((size_t)Dc * Hc * 2);
    unsigned short* Wop_b   = (unsigned short*)alloc((size_t)Dc * Hc * 2);
    unsigned short* Wpost_b = (unsigned short*)alloc((size_t)Ac * Hc * 2);
    unsigned short* WapT_b  = (unsigned short*)alloc((size_t)Ac * Hc * 2);
    unsigned short* WepT_b  = (unsigned short*)alloc((size_t)Ac * Hc * 2);
    unsigned short* Wdap_b  = (unsigned short*)alloc((size_t)Dc * Ac * 2);
    unsigned short* Wopep_b = (unsigned short*)alloc((size_t)Dc * Ac * 2);
    unsigned short* Aexp_b  = (unsigned short*)alloc((size_t)Ec * Ac * Ac * 2);
    unsigned short* pre_b   = (unsigned short*)alloc((size_t)Nc * Ac * 2);
    unsigned short* hidden  = (unsigned short*)alloc((size_t)Nc * Hc * 2);
    unsigned short* adapt_in  = (unsigned short*)alloc((size_t)Nc * Ac * 2);
    unsigned short* adapt_inT = (unsigned short*)alloc((size_t)Nc * Ac * 2);
    unsigned short* adapt_out = (unsigned short*)alloc((size_t)Nc * Ac * 2);
    unsigned short* adaptb    = (unsigned short*)alloc((size_t)Nc * Ac * 2);
    unsigned short* h2        = (unsigned short*)alloc((size_t)Nc * Ac * 2);

    float* wprepP = h_dense;   // [4 split][2 pair][1024*128] f32
    float* postP  = h_dense;   // [4][4096*128] f32
    float* adaptP = h_dense;   // [8][2][2048*128] f32

    // ---- merged weight prep + router (byte-proportional prep blocks) ----
    PrepArgs pa;
    pa.csrc[0] = W_down;  pa.cdst[0] = Wd_b;    pa.cn4[0] = Dc * Hc / 4;
    pa.csrc[1] = W_oproj; pa.cdst[1] = Wop_b;   pa.cn4[1] = Dc * Hc / 4;
    pa.csrc[2] = W_post;  pa.cdst[2] = Wpost_b; pa.cn4[2] = Ac * Hc / 4;
    pa.csrc[3] = A_exp;   pa.cdst[3] = Aexp_b;  pa.cn4[3] = Ec * Ac * Ac / 4;
    pa.Wg = W_gate; pa.Wu = W_up; pa.Wpre = W_pre; pa.Wcat = Wcat_b;
    pa.tin0 = W_aproj; pa.tin1 = W_eproj; pa.tout0 = WapT_b; pa.tout1 = WepT_b;
    preprt_k<<<NPREP + RBLK, 256, 0, stream>>>(pa, x, W_rg, W_re, eidx, fw, dmsum, rpart, xb);
    loss_k<<<1, 512, 0, stream>>>(rpart, out + (size_t)Nc * Dc);

    // ---- Wdap/Wopep split-K (4x512), z=(pair,split), then alpha=0.1 reduce ----
    mgemm64<<<dim3(2, 8, 8), 256, 0, stream>>>(Wd_b, WapT_b, wprepP, Ac, 512, Hc, Hc,
        2,
        (long long)Dc * Hc, (long long)Ac * Hc, (long long)Dc * Ac,
        512, 512, (long long)2 * Dc * Ac);
    reduce_k<4, 1><<<256, 256, 0, stream>>>(wprepP, Wdap_b,
        (long long)2 * Dc * Ac, 2 * Dc * Ac / 4, 0.1f);

    // ---- fused gate+up+pre (BK=64, PR=8 x PC=3 panel swizzle) ----
    mgemm<9><<<dim3(33, 32), 256, 0, stream>>>(xb, Wcat_b, hidden, 2 * Hc + Ac, Dc, Dc, Dc,
        8, 3, 0.f, pre, pre_b, 0, 0, 0);
    lntr_k<<<dim3(Sc / 64, Bc), 256, 0, stream>>>(pre, adapt_in, adapt_inT, ln_g, ln_b);

    // ---- post split-K via mgemm (single 128-wide x-tile, z=4 K-splits) ----
    mgemm<0><<<dim3(1, 32, 4), 256, 0, stream>>>(hidden, Wpost_b, postP, Ac, 512, Hc, Hc,
        4, 1, 0.f, nullptr, nullptr, 512, 512, (long long)Nc * Ac);
    redln_k<<<Nc, 64, 0, stream>>>(postP, adapt_out, ln_g, ln_b, (long long)Nc * Ac);

    // ---- dense expert adapter via mgemm: h_dense[e] = pre_b @ A_exp[e]^T ----
    mgemm<0><<<dim3(1, 32, Ec), 256, 0, stream>>>(pre_b, Aexp_b, h_dense, Ac, Ac, Ac, Ac,
        4, 1, 0.f, nullptr, nullptr, 0, (long long)Ac * Ac, (long long)Nc * Ac);
    combine_k<<<Nc, 128, 0, stream>>>(h_dense, ln_g_e, ln_b_e, eidx, fw, h2);

    // ---- fused aw+adapt (direct-global fragments, QBLK=64, 512 blocks) ----
    fadapt_k<<<dim3(8, 32, 2), 256, 0, stream>>>(adapt_in, adapt_out, adapt_inT, adaptP);
    reduce_k<8, 1><<<512, 256, 0, stream>>>(adaptP, adaptb,
        (long long)2 * Sc * Ac, 2 * Sc * Ac / 4, 1.f);

    // ---- final fused (BK=64, PR=4 x PC=4 panel swizzle) ----
    final_k<<<dim3(Dc / 64, Nc / 128), 256, 0, stream>>>(
        hidden, Wd_b, adaptb, Wdap_b, h2, Wopep_b, dmsum, out);
}